// Round 3
// baseline (8215.557 us; speedup 1.0000x reference)
//
#include <hip/hip_runtime.h>
#include <cstddef>

// ---------------- numerics helpers (mirror reference FP32 op order) ----------------

__device__ __forceinline__ float sqd(float x, float y, float z, float qx, float qy, float qz) {
#pragma clang fp contract(off)
    float dx = x - qx, dy = y - qy, dz = z - qz;
    return (dx * dx + dy * dy) + dz * dz;
}

__device__ __forceinline__ float sum3sq(float x, float y, float z) {
#pragma clang fp contract(off)
    return (x * x + y * y) + z * z;
}

// reference _sqdist: sum(a^2) + sum(b^2) - 2*dot(a,b)
__device__ __forceinline__ float sqd_dot(float ax, float ay, float az, float sa_,
                                         float bx, float by, float bz) {
#pragma clang fp contract(off)
    float sb = (bx * bx + by * by) + bz * bz;
    float dt = (ax * bx + ay * by) + az * bz;
    return (sa_ + sb) - 2.0f * dt;
}

// ---------------- FPS, large (N=32768, npoint=512): exact bucketed pruning ----------------
// One 512-thread block per batch; thread t owns bucket t (8x8x8 grid over per-batch bbox).
// Points counting-sorted into ws as float4{x,y,z,bitcast(origidx)}; mind[] in LDS, each
// thread touching only its own bucket's range (no sync needed on mind). Per iteration:
// thread skips its bucket when d2min(q,box) >= bucket_max_mind (provable fminf no-op,
// conservative margin); otherwise rescans its bucket serially in registers. Global argmax
// = per-wave shfl reduce of register caches (skipped for waves with no update; redv/redi/
// redb persist) + 8-entry scan. Ordering (val desc, origidx asc) == reference argmax.

__global__ __launch_bounds__(512) void fps_bucketed(const float* __restrict__ xyz,
                                                    int* __restrict__ inds,
                                                    float4* __restrict__ sortedAll,
                                                    int* __restrict__ bucketOfAll) {
    const int b = blockIdx.x, t = threadIdx.x, w = t >> 6, l = t & 63;
    const float* __restrict__ P = xyz + (size_t)b * 32768 * 3;
    float4* __restrict__ SP = sortedAll + (size_t)b * 32768;
    int* __restrict__ BO = bucketOfAll + (size_t)b * 32768;

    __shared__ float mind[32768];
    __shared__ int   offS[512];
    __shared__ int   cntS[512];
    __shared__ int   curS[512];
    __shared__ float bxS[512], byS[512], bzS[512];
    __shared__ float redv[8];
    __shared__ int   redi[8];
    __shared__ int   redb[8];
    __shared__ float bbS[6];
    __shared__ float scr[48];

    // ---- pass 1: per-batch bbox ----
    float mnx = 1e30f, mny = 1e30f, mnz = 1e30f;
    float mxx = -1e30f, mxy = -1e30f, mxz = -1e30f;
    for (int p = t; p < 32768; p += 512) {
        const float x = P[3 * p], y = P[3 * p + 1], z = P[3 * p + 2];
        mnx = fminf(mnx, x); mxx = fmaxf(mxx, x);
        mny = fminf(mny, y); mxy = fmaxf(mxy, y);
        mnz = fminf(mnz, z); mxz = fmaxf(mxz, z);
    }
#pragma unroll
    for (int o = 1; o < 64; o <<= 1) {
        mnx = fminf(mnx, __shfl_xor(mnx, o)); mxx = fmaxf(mxx, __shfl_xor(mxx, o));
        mny = fminf(mny, __shfl_xor(mny, o)); mxy = fmaxf(mxy, __shfl_xor(mxy, o));
        mnz = fminf(mnz, __shfl_xor(mnz, o)); mxz = fmaxf(mxz, __shfl_xor(mxz, o));
    }
    if (l == 0) {
        scr[w] = mnx; scr[8 + w] = mny; scr[16 + w] = mnz;
        scr[24 + w] = mxx; scr[32 + w] = mxy; scr[40 + w] = mxz;
    }
    __syncthreads();
    if (t == 0) {
        float a0 = 1e30f, a1 = 1e30f, a2 = 1e30f, a3 = -1e30f, a4 = -1e30f, a5 = -1e30f;
        for (int i = 0; i < 8; ++i) {
            a0 = fminf(a0, scr[i]);      a1 = fminf(a1, scr[8 + i]);
            a2 = fminf(a2, scr[16 + i]); a3 = fmaxf(a3, scr[24 + i]);
            a4 = fmaxf(a4, scr[32 + i]); a5 = fmaxf(a5, scr[40 + i]);
        }
        bbS[0] = a0; bbS[1] = a1; bbS[2] = a2; bbS[3] = a3; bbS[4] = a4; bbS[5] = a5;
    }
    __syncthreads();
    const float bx0 = bbS[0], by0 = bbS[1], bz0 = bbS[2];
    const float ex = bbS[3] - bx0, ey = bbS[4] - by0, ez = bbS[5] - bz0;
    const float ivx = ex > 1e-20f ? 8.0f / ex : 0.0f;
    const float ivy = ey > 1e-20f ? 8.0f / ey : 0.0f;
    const float ivz = ez > 1e-20f ? 8.0f / ez : 0.0f;

    // ---- pass 2: histogram + bucket-id write ----
    cntS[t] = 0;
    __syncthreads();
    for (int p = t; p < 32768; p += 512) {
        const float x = P[3 * p], y = P[3 * p + 1], z = P[3 * p + 2];
        const int ix = min(7, (int)((x - bx0) * ivx));
        const int iy = min(7, (int)((y - by0) * ivy));
        const int iz = min(7, (int)((z - bz0) * ivz));
        const int bu = (iz * 8 + iy) * 8 + ix;
        BO[p] = bu;
        atomicAdd(&cntS[bu], 1);
    }
    __syncthreads();

    // ---- exclusive scan (Hillis-Steele) ----
    offS[t] = cntS[t];
    __syncthreads();
    for (int d = 1; d < 512; d <<= 1) {
        const int v = (t >= d) ? offS[t - d] : 0;
        __syncthreads();
        offS[t] += v;
        __syncthreads();
    }
    const int myexc = offS[t] - cntS[t];
    offS[t] = myexc;
    curS[t] = myexc;
    __syncthreads();

    // ---- pass 3: scatter + mind init + per-thread cache init ----
    for (int p = t; p < 32768; p += 512) {
        const float x = P[3 * p], y = P[3 * p + 1], z = P[3 * p + 2];
        const int bu = BO[p];
        const int pos = atomicAdd(&curS[bu], 1);
        SP[pos] = make_float4(x, y, z, __int_as_float(p));
    }
    for (int s = t; s < 32768; s += 512) mind[s] = 1e30f;
    bxS[t] = 0.f; byS[t] = 0.f; bzS[t] = 0.f;
    if (t < 8) { redv[t] = -2.0f; redi[t] = 0x7fffffff; redb[t] = 0; }
    if (t == 0) inds[b * 512] = 0;
    __syncthreads();

    // per-thread owned bucket = t
    const int base_own = offS[t], cnt_own = cntS[t];
    const int oix = t & 7, oiy = (t >> 3) & 7, oiz = t >> 6;
    const float gwx = ex * 0.125f, gwy = ey * 0.125f, gwz = ez * 0.125f;
    const float x0o = bx0 + oix * gwx, x1o = bx0 + (oix + 1) * gwx;
    const float y0o = by0 + oiy * gwy, y1o = by0 + (oiy + 1) * gwy;
    const float z0o = bz0 + oiz * gwz, z1o = bz0 + (oiz + 1) * gwz;

    float bmax_reg = (cnt_own > 0) ? 1e30f : -1.0f;
    int   barg_reg = 0x7fffffff;
    float qx = P[0], qy = P[1], qz = P[2];

    for (int k = 1; k < 512; ++k) {
        // ---- phase A: every thread rescans its own bucket if potentially affected ----
        const float ddx = fmaxf(fmaxf(x0o - qx, qx - x1o), 0.0f);
        const float ddy = fmaxf(fmaxf(y0o - qy, qy - y1o), 0.0f);
        const float ddz = fmaxf(fmaxf(z0o - qz, qz - z1o), 0.0f);
        const float d2m = ddx * ddx + ddy * ddy + ddz * ddz;
        const bool act = (cnt_own > 0) && (d2m <= bmax_reg * 1.0001f + 1e-9f);
        if (act) {
            float vb = -1.0f; int ib = 0x7fffffff; int bp = 0;
#pragma unroll 4
            for (int c = 0; c < cnt_own; ++c) {
                const float4 pt = SP[base_own + c];
                const float m = mind[base_own + c];
                const float d2 = sqd(pt.x, pt.y, pt.z, qx, qy, qz);
                const float nm = fminf(m, d2);
                mind[base_own + c] = nm;
                const int oi = __float_as_int(pt.w);
                if (nm > vb || (nm == vb && oi < ib)) { vb = nm; ib = oi; bp = c; }
            }
            bmax_reg = vb; barg_reg = ib;
            const float4 wpt = SP[base_own + bp];
            bxS[t] = wpt.x; byS[t] = wpt.y; bzS[t] = wpt.z;
        }
        // ---- phase B: global argmax over per-thread caches ----
        const unsigned long long um = __ballot(act);
        if (um) {
            float v = bmax_reg; int ii = barg_reg; int bb = t;
#pragma unroll
            for (int o = 1; o < 64; o <<= 1) {
                const float ov = __shfl_xor(v, o);
                const int oi2 = __shfl_xor(ii, o);
                const int ob = __shfl_xor(bb, o);
                if (ov > v || (ov == v && oi2 < ii)) { v = ov; ii = oi2; bb = ob; }
            }
            if (l == 0) { redv[w] = v; redi[w] = ii; redb[w] = bb; }
        }
        __syncthreads();  // B1: caches + wave candidates visible
        float wv = redv[0]; int wi = redi[0], wb = redb[0];
#pragma unroll
        for (int w2 = 1; w2 < 8; ++w2) {
            const float v2 = redv[w2]; const int i2 = redi[w2]; const int b2 = redb[w2];
            if (v2 > wv || (v2 == wv && i2 < wi)) { wv = v2; wi = i2; wb = b2; }
        }
        if (t == 0) inds[b * 512 + k] = wi;
        qx = bxS[wb]; qy = byS[wb]; qz = bzS[wb];
        __syncthreads();  // B2: bxS reads done before next-iter writes
    }
}

// ---------------- FPS, small (N<=512), one wave per batch, all in registers ----------------

template <int N, int NPOINT>
__global__ __launch_bounds__(64) void fps_small(const float* __restrict__ pts,
                                                int* __restrict__ inds) {
    constexpr int PPT = N / 64;
    const int b = blockIdx.x, l = threadIdx.x;
    const float* __restrict__ P = pts + (size_t)b * N * 3;
    float px[PPT], py[PPT], pz[PPT], md[PPT];
#pragma unroll
    for (int j = 0; j < PPT; ++j) {
        const int p = l + 64 * j;
        px[j] = P[p * 3]; py[j] = P[p * 3 + 1]; pz[j] = P[p * 3 + 2];
        md[j] = 1e30f;
    }
    float qx = P[0], qy = P[1], qz = P[2];
    if (l == 0) inds[b * NPOINT] = 0;
    for (int k = 1; k < NPOINT; ++k) {
        float bv = -1.0f;
        int   bi = 0;
#pragma unroll
        for (int j = 0; j < PPT; ++j) {
            md[j] = fminf(md[j], sqd(px[j], py[j], pz[j], qx, qy, qz));
            if (md[j] > bv) { bv = md[j]; bi = l + 64 * j; }
        }
#pragma unroll
        for (int off = 1; off < 64; off <<= 1) {
            float ov = __shfl_xor(bv, off);
            int   oi = __shfl_xor(bi, off);
            if (ov > bv || (ov == bv && oi < bi)) { bv = ov; bi = oi; }
        }
        if (l == 0) inds[b * NPOINT + k] = bi;
        const int ol = bi & 63, js = bi >> 6;
        float sx = px[0], sy = py[0], sz = pz[0];
#pragma unroll
        for (int j = 1; j < PPT; ++j) {
            if (j == js) { sx = px[j]; sy = py[j]; sz = pz[j]; }
        }
        qx = __shfl(sx, ol); qy = __shfl(sy, ol); qz = __shfl(sz, ol);
    }
}

// ---------------- gather 3-float points by index ----------------

__global__ void gather3(const float* __restrict__ src, const int* __restrict__ inds,
                        float* __restrict__ dst, int Nsrc, int M, int total) {
    const int t = blockIdx.x * 256 + threadIdx.x;
    if (t >= total) return;
    const int b = t / M;
    const int n = inds[t];
    const float* s = src + ((size_t)b * Nsrc + n) * 3;
    float* d = dst + (size_t)t * 3;
    d[0] = s[0]; d[1] = s[1]; d[2] = s[2];
}

// ---------------- ball query: first NS points with d2 < r2, pad with first hit ----------------

template <int NS>
__global__ __launch_bounds__(256) void ball_query_k(const float* __restrict__ xyz,
                                                    const float* __restrict__ centers,
                                                    int* __restrict__ out,
                                                    int N, int M, float r2) {
    const int wv = blockIdx.x * 4 + (threadIdx.x >> 6);
    const int l  = threadIdx.x & 63;
    const int b  = wv / M;
    const float* cp = centers + (size_t)wv * 3;
    const float ax = cp[0], ay = cp[1], az = cp[2];
    const float sa_ = sum3sq(ax, ay, az);
    const float* __restrict__ P = xyz + (size_t)b * N * 3;
    int* o = out + (size_t)wv * NS;

    int cnt = 0, first = -1;
    float nx = P[l * 3], ny = P[l * 3 + 1], nz = P[l * 3 + 2];
    for (int i0 = 0; i0 < N; i0 += 64) {
        const float bx = nx, by = ny, bz = nz;
        if (i0 + 64 < N) {
            const int ip = (i0 + 64 + l) * 3;
            nx = P[ip]; ny = P[ip + 1]; nz = P[ip + 2];
        }
        const float d2 = sqd_dot(ax, ay, az, sa_, bx, by, bz);
        const bool in = d2 < r2;
        const unsigned long long mask = __ballot(in);
        if (first < 0 && mask != 0ull) first = i0 + __builtin_ctzll(mask);
        const int pos = cnt + __popcll(mask & ((1ull << l) - 1ull));
        if (in && pos < NS) o[pos] = i0 + l;
        cnt += __popcll(mask);
        if (cnt >= NS) break;
    }
    if (first < 0) first = 0;
    for (int p2 = cnt + l; p2 < NS; p2 += 64) o[p2] = first;
}

// ---------------- fused SA for sa1: gather + normalize + 3-layer MLP + max ----------------

template <int NS, int CF, int C1, int C2, int C3>
__global__ __launch_bounds__(64) void sa_fused(
    const float* __restrict__ xyz, const float* __restrict__ feats,
    const float* __restrict__ centers, const int* __restrict__ idx,
    const float* __restrict__ w0, const float* __restrict__ b0,
    const float* __restrict__ w1, const float* __restrict__ b1,
    const float* __restrict__ w2, const float* __restrict__ b2,
    float* __restrict__ outf, int N, int M, float r) {
    constexpr int CIN = 3 + CF;
    constexpr int CL  = (C3 > 0) ? C3 : C2;
    constexpr int CPB = 64 / NS;
    const int tid = threadIdx.x;
    const int ci = tid / NS, s = tid % NS;
    const int gc = blockIdx.x * CPB + ci;
    const int b  = gc / M;
    const float* cp = centers + (size_t)gc * 3;
    const float cx = cp[0], cy = cp[1], cz = cp[2];
    const int n = idx[(size_t)gc * NS + s];
    const float* pp = xyz + ((size_t)b * N + n) * 3;
    float gi[CIN];
    gi[0] = (pp[0] - cx) / r; gi[1] = (pp[1] - cy) / r; gi[2] = (pp[2] - cz) / r;
    if constexpr (CF > 0) {
        const float* fr = feats + ((size_t)b * N + n) * CF;
#pragma unroll
        for (int c = 0; c < CF; ++c) gi[3 + c] = fr[c];
    }
    float h1[C1];
#pragma unroll
    for (int o = 0; o < C1; ++o) {
        float acc = b0[o];
#pragma unroll
        for (int k = 0; k < CIN; ++k) acc += gi[k] * w0[k * C1 + o];
        h1[o] = fmaxf(acc, 0.f);
    }
    float h2[C2];
#pragma unroll
    for (int o = 0; o < C2; ++o) {
        float acc = b1[o];
#pragma unroll
        for (int k = 0; k < C1; ++k) acc += h1[k] * w1[k * C2 + o];
        h2[o] = fmaxf(acc, 0.f);
    }
    float hl[CL];
    if constexpr (C3 > 0) {
#pragma unroll
        for (int o = 0; o < C3; ++o) {
            float acc = b2[o];
#pragma unroll
            for (int k = 0; k < C2; ++k) acc += h2[k] * w2[k * C3 + o];
            hl[o] = fmaxf(acc, 0.f);
        }
    } else {
#pragma unroll
        for (int o = 0; o < CL; ++o) hl[o] = h2[o];
    }
    __shared__ float hs[64][CL + 1];
#pragma unroll
    for (int c = 0; c < CL; ++c) hs[tid][c] = hl[c];
    __syncthreads();
    for (int cc = 0; cc < CPB; ++cc) {
        for (int c = tid; c < CL; c += 64) {
            float mx = hs[cc * NS][c];
            for (int s2 = 1; s2 < NS; ++s2) mx = fmaxf(mx, hs[cc * NS + s2][c]);
            outf[(size_t)(blockIdx.x * CPB + cc) * CL + c] = mx;
        }
    }
}

// ---------------- build grouped input rows: [(p-c)/r | feats[n]] ----------------

__global__ void build_g(const float* __restrict__ xyz, const float* __restrict__ feats,
                        const float* __restrict__ centers, const int* __restrict__ idx,
                        float* __restrict__ g, int N, int M, int NS, int CF, float r) {
    const int row = blockIdx.x * 4 + (threadIdx.x >> 6);
    const int l   = threadIdx.x & 63;
    const int gc  = row / NS;
    const int b   = gc / M;
    const int n   = idx[row];
    const float* cp = centers + (size_t)gc * 3;
    const float* pp = xyz + ((size_t)b * N + n) * 3;
    float* go = g + (size_t)row * (3 + CF);
    if (l < 3) go[l] = (pp[l] - cp[l]) / r;
    for (int c = l; c < CF; c += 64) go[3 + c] = feats[((size_t)b * N + n) * CF + c];
}

// ---------------- dense layer + relu ----------------

__global__ void dense_relu(const float* __restrict__ X, const float* __restrict__ Wm,
                           const float* __restrict__ bias, float* __restrict__ Y,
                           int M, int CI, int CO) {
    const int co = blockIdx.x * 64 + threadIdx.x;
    const int m  = blockIdx.y * 4 + threadIdx.y;
    const float* x = X + (size_t)m * CI;
    float acc = bias[co];
#pragma unroll 4
    for (int k = 0; k < CI; ++k) acc += x[k] * Wm[(size_t)k * CO + co];
    Y[(size_t)m * CO + co] = fmaxf(acc, 0.f);
}

// ---------------- max over samples ----------------

__global__ void max_ns(const float* __restrict__ H, float* __restrict__ F,
                       int BM, int NS, int C) {
    const int tid = blockIdx.x * 256 + threadIdx.x;
    if (tid >= BM * C) return;
    const int bm = tid / C, c = tid % C;
    const float* h = H + ((size_t)bm * NS) * C + c;
    float mx = h[0];
    for (int s = 1; s < NS; ++s) mx = fmaxf(mx, h[(size_t)s * C]);
    F[tid] = mx;
}

// ---------------- FP: 3-NN + inverse-distance weights ----------------

__global__ void fp_nn(const float* __restrict__ unk, const float* __restrict__ kn,
                      int* __restrict__ nni, float* __restrict__ nnw, int NU, int NK) {
    const int t = blockIdx.x * blockDim.x + threadIdx.x;
    const int b = t / NU;
    const float* u = unk + (size_t)t * 3;
    const float ax = u[0], ay = u[1], az = u[2];
    const float sa_ = sum3sq(ax, ay, az);
    const float* K = kn + (size_t)b * NK * 3;
    float v0 = 1e30f, v1 = 1e30f, v2 = 1e30f;
    int   j0 = 0, j1 = 0, j2 = 0;
    for (int k = 0; k < NK; ++k) {
        const float d2 = sqd_dot(ax, ay, az, sa_, K[k * 3], K[k * 3 + 1], K[k * 3 + 2]);
        if (d2 < v0)      { v2 = v1; j2 = j1; v1 = v0; j1 = j0; v0 = d2; j0 = k; }
        else if (d2 < v1) { v2 = v1; j2 = j1; v1 = d2; j1 = k; }
        else if (d2 < v2) { v2 = d2; j2 = k; }
    }
    const float d0 = fmaxf(v0, 0.f), d1 = fmaxf(v1, 0.f), dd2 = fmaxf(v2, 0.f);
    float w0 = 1.f / (d0 + 1e-8f), w1 = 1.f / (d1 + 1e-8f), w2 = 1.f / (dd2 + 1e-8f);
    const float s = (w0 + w1) + w2;
    nnw[t * 3] = w0 / s; nnw[t * 3 + 1] = w1 / s; nnw[t * 3 + 2] = w2 / s;
    nni[t * 3] = j0; nni[t * 3 + 1] = j1; nni[t * 3 + 2] = j2;
}

// ---------------- FP: concat [feats1 | interp(feats2)] ----------------

__global__ void interp_concat(const float* __restrict__ f1, const float* __restrict__ f2,
                              const int* __restrict__ nni, const float* __restrict__ nnw,
                              float* __restrict__ X, int NU, int NK, int C1c, int C2c) {
    const int row = blockIdx.x * 4 + (threadIdx.x >> 6);
    const int l   = threadIdx.x & 63;
    const int b   = row / NU;
    const int i0 = nni[row * 3], i1 = nni[row * 3 + 1], i2 = nni[row * 3 + 2];
    const float w0 = nnw[row * 3], w1 = nnw[row * 3 + 1], w2 = nnw[row * 3 + 2];
    float* xo = X + (size_t)row * (C1c + C2c);
    for (int c = l; c < C1c; c += 64) xo[c] = f1[(size_t)row * C1c + c];
    const float* a  = f2 + ((size_t)b * NK + i0) * C2c;
    const float* bb = f2 + ((size_t)b * NK + i1) * C2c;
    const float* cc = f2 + ((size_t)b * NK + i2) * C2c;
    for (int c = l; c < C2c; c += 64) xo[C1c + c] = (w0 * a[c] + w1 * bb[c]) + w2 * cc[c];
}

__global__ void copyf(const float* __restrict__ src, float* __restrict__ dst, int n) {
    const int i = blockIdx.x * 256 + threadIdx.x;
    if (i < n) dst[i] = src[i];
}

// ---------------- host launcher ----------------

extern "C" void kernel_launch(void* const* d_in, const int* in_sizes, int n_in,
                              void* d_out, int out_size, void* d_ws, size_t ws_size,
                              hipStream_t stream) {
    const float* xyz  = (const float*)d_in[0];
    const float* s1w0 = (const float*)d_in[1],  *s1b0 = (const float*)d_in[2];
    const float* s1w1 = (const float*)d_in[3],  *s1b1 = (const float*)d_in[4];
    const float* s1w2 = (const float*)d_in[5],  *s1b2 = (const float*)d_in[6];
    const float* s2w0 = (const float*)d_in[7],  *s2b0 = (const float*)d_in[8];
    const float* s2w1 = (const float*)d_in[9],  *s2b1 = (const float*)d_in[10];
    const float* s3w0 = (const float*)d_in[11], *s3b0 = (const float*)d_in[12];
    const float* s3w1 = (const float*)d_in[13], *s3b1 = (const float*)d_in[14];
    const float* s4w0 = (const float*)d_in[15], *s4b0 = (const float*)d_in[16];
    const float* s4w1 = (const float*)d_in[17], *s4b1 = (const float*)d_in[18];
    const float* p1w0 = (const float*)d_in[19], *p1b0 = (const float*)d_in[20];
    const float* p1w1 = (const float*)d_in[21], *p1b1 = (const float*)d_in[22];
    const float* p2w0 = (const float*)d_in[23], *p2b0 = (const float*)d_in[24];
    const float* p2w1 = (const float*)d_in[25], *p2b1 = (const float*)d_in[26];
    float* out = (float*)d_out;
    float* W = (float*)d_ws;

    size_t off = 0;
    auto A_ = [&](size_t n) { size_t o = off; off += (n + 63) & ~(size_t)63; return o; };
    const size_t o_inds1 = A_(4 * 512);
    const size_t o_xyz1  = A_(4 * 512 * 3);
    const size_t o_idx1  = A_(4 * 512 * 64);
    const size_t o_f1    = A_(4 * 512 * 64);
    const size_t o_inds2 = A_(4 * 256);
    const size_t o_xyz2  = A_(4 * 256 * 3);
    const size_t o_idx2  = A_(4 * 256 * 32);
    const size_t o_f2    = A_(4 * 256 * 128);
    const size_t o_inds3 = A_(4 * 64);
    const size_t o_xyz3  = A_(4 * 64 * 3);
    const size_t o_idx3  = A_(4 * 64 * 16);
    const size_t o_f3    = A_(4 * 64 * 256);
    const size_t o_inds4 = A_(4 * 16);
    const size_t o_xyz4  = A_(4 * 16 * 3);
    const size_t o_idx4  = A_(4 * 16 * 16);
    const size_t o_f4    = A_(4 * 16 * 256);
    const size_t o_f5    = A_(4 * 64 * 128);
    const size_t o_nni1  = A_(4 * 64 * 3);
    const size_t o_nnw1  = A_(4 * 64 * 3);
    const size_t o_nni2  = A_(4 * 256 * 3);
    const size_t o_nnw2  = A_(4 * 256 * 3);
    const size_t o_sort  = A_((size_t)4 * 32768 * 4);  // float4 sorted points
    const size_t o_bof   = A_((size_t)4 * 32768);      // bucket id per point
    const size_t o_bufA  = A_((size_t)32768 * 128);    // 16 MiB arena
    const size_t o_bufB  = A_((size_t)32768 * 64);     //  8 MiB arena
    if (off * sizeof(float) > ws_size) return;  // fail loudly (validation will catch)

    int*   inds1 = (int*)(W + o_inds1); float* xyz1 = W + o_xyz1;
    int*   idx1  = (int*)(W + o_idx1);  float* f1   = W + o_f1;
    int*   inds2 = (int*)(W + o_inds2); float* xyz2 = W + o_xyz2;
    int*   idx2  = (int*)(W + o_idx2);  float* f2   = W + o_f2;
    int*   inds3 = (int*)(W + o_inds3); float* xyz3 = W + o_xyz3;
    int*   idx3  = (int*)(W + o_idx3);  float* f3   = W + o_f3;
    int*   inds4 = (int*)(W + o_inds4); float* xyz4 = W + o_xyz4;
    int*   idx4  = (int*)(W + o_idx4);  float* f4   = W + o_f4;
    float* f5    = W + o_f5;
    int*   nni1  = (int*)(W + o_nni1);  float* nnw1 = W + o_nnw1;
    int*   nni2  = (int*)(W + o_nni2);  float* nnw2 = W + o_nnw2;
    float4* sortP = (float4*)(W + o_sort);
    int*    bof   = (int*)(W + o_bof);
    float* bufA  = W + o_bufA;
    float* bufB  = W + o_bufB;

    // -------- sa1: npoint=512, r=0.1, ns=64, MLP 3->32->32->64 --------
    fps_bucketed<<<4, 512, 0, stream>>>(xyz, inds1, sortP, bof);
    gather3<<<8, 256, 0, stream>>>(xyz, inds1, xyz1, 32768, 512, 2048);
    ball_query_k<64><<<512, 256, 0, stream>>>(xyz, xyz1, idx1, 32768, 512, (float)(0.1 * 0.1));
    sa_fused<64, 0, 32, 32, 64><<<2048, 64, 0, stream>>>(
        xyz, nullptr, xyz1, idx1, s1w0, s1b0, s1w1, s1b1, s1w2, s1b2, f1, 32768, 512, 0.1f);

    // -------- sa2: npoint=256, r=0.2, ns=32, MLP 67->64->128 --------
    fps_small<512, 256><<<4, 64, 0, stream>>>(xyz1, inds2);
    gather3<<<4, 256, 0, stream>>>(xyz1, inds2, xyz2, 512, 256, 1024);
    ball_query_k<32><<<256, 256, 0, stream>>>(xyz1, xyz2, idx2, 512, 256, (float)(0.2 * 0.2));
    build_g<<<32768 / 4, 256, 0, stream>>>(xyz1, f1, xyz2, idx2, bufA, 512, 256, 32, 64, 0.2f);
    dense_relu<<<dim3(1, 32768 / 4), dim3(64, 4), 0, stream>>>(bufA, s2w0, s2b0, bufB, 32768, 67, 64);
    dense_relu<<<dim3(2, 32768 / 4), dim3(64, 4), 0, stream>>>(bufB, s2w1, s2b1, bufA, 32768, 64, 128);
    max_ns<<<(1024 * 128 + 255) / 256, 256, 0, stream>>>(bufA, f2, 1024, 32, 128);

    // -------- sa3: npoint=64, r=0.4, ns=16, MLP 131->128->256 --------
    fps_small<256, 64><<<4, 64, 0, stream>>>(xyz2, inds3);
    gather3<<<1, 256, 0, stream>>>(xyz2, inds3, xyz3, 256, 64, 256);
    ball_query_k<16><<<64, 256, 0, stream>>>(xyz2, xyz3, idx3, 256, 64, (float)(0.4 * 0.4));
    build_g<<<4096 / 4, 256, 0, stream>>>(xyz2, f2, xyz3, idx3, bufA, 256, 64, 16, 128, 0.4f);
    dense_relu<<<dim3(2, 4096 / 4), dim3(64, 4), 0, stream>>>(bufA, s3w0, s3b0, bufB, 4096, 131, 128);
    dense_relu<<<dim3(4, 4096 / 4), dim3(64, 4), 0, stream>>>(bufB, s3w1, s3b1, bufA, 4096, 128, 256);
    max_ns<<<(256 * 256 + 255) / 256, 256, 0, stream>>>(bufA, f3, 256, 16, 256);

    // -------- sa4: npoint=16, r=0.8, ns=16, MLP 259->256->256 --------
    fps_small<64, 16><<<4, 64, 0, stream>>>(xyz3, inds4);
    gather3<<<1, 256, 0, stream>>>(xyz3, inds4, xyz4, 64, 16, 64);
    ball_query_k<16><<<16, 256, 0, stream>>>(xyz3, xyz4, idx4, 64, 16, (float)(0.8 * 0.8));
    build_g<<<1024 / 4, 256, 0, stream>>>(xyz3, f3, xyz4, idx4, bufA, 64, 16, 16, 256, 0.8f);
    dense_relu<<<dim3(4, 1024 / 4), dim3(64, 4), 0, stream>>>(bufA, s4w0, s4b0, bufB, 1024, 259, 256);
    dense_relu<<<dim3(4, 1024 / 4), dim3(64, 4), 0, stream>>>(bufB, s4w1, s4b1, bufA, 1024, 256, 256);
    max_ns<<<(64 * 256 + 255) / 256, 256, 0, stream>>>(bufA, f4, 64, 16, 256);

    // -------- fp1: xyz3 <- xyz4, [f3 | interp(f4)] 512->256->128 --------
    fp_nn<<<1, 256, 0, stream>>>(xyz3, xyz4, nni1, nnw1, 64, 16);
    interp_concat<<<256 / 4, 256, 0, stream>>>(f3, f4, nni1, nnw1, bufA, 64, 16, 256, 256);
    dense_relu<<<dim3(4, 256 / 4), dim3(64, 4), 0, stream>>>(bufA, p1w0, p1b0, bufB, 256, 512, 256);
    dense_relu<<<dim3(2, 256 / 4), dim3(64, 4), 0, stream>>>(bufB, p1w1, p1b1, f5, 256, 256, 128);

    // -------- fp2: xyz2 <- xyz3, [f2 | interp(f5)] 256->128->64 --------
    fp_nn<<<4, 256, 0, stream>>>(xyz2, xyz3, nni2, nnw2, 256, 64);
    interp_concat<<<1024 / 4, 256, 0, stream>>>(f2, f5, nni2, nnw2, bufA, 256, 64, 128, 128);
    dense_relu<<<dim3(2, 1024 / 4), dim3(64, 4), 0, stream>>>(bufA, p2w0, p2b0, bufB, 1024, 256, 128);
    dense_relu<<<dim3(1, 1024 / 4), dim3(64, 4), 0, stream>>>(bufB, p2w1, p2b1, out, 1024, 128, 64);

    // -------- outputs: [f (4x256x64) | xyz2 (4x256x3)] --------
    copyf<<<12, 256, 0, stream>>>(xyz2, out + 65536, 3072);
}

// Round 4
// 6993.346 us; speedup vs baseline: 1.1748x; 1.1748x over previous
//
#include <hip/hip_runtime.h>
#include <cstddef>

// ---------------- numerics helpers (mirror reference FP32 op order) ----------------

__device__ __forceinline__ float sqd(float x, float y, float z, float qx, float qy, float qz) {
#pragma clang fp contract(off)
    float dx = x - qx, dy = y - qy, dz = z - qz;
    return (dx * dx + dy * dy) + dz * dz;
}

__device__ __forceinline__ float sum3sq(float x, float y, float z) {
#pragma clang fp contract(off)
    return (x * x + y * y) + z * z;
}

// reference _sqdist: sum(a^2) + sum(b^2) - 2*dot(a,b)
__device__ __forceinline__ float sqd_dot(float ax, float ay, float az, float sa_,
                                         float bx, float by, float bz) {
#pragma clang fp contract(off)
    float sb = (bx * bx + by * by) + bz * bz;
    float dt = (ax * bx + ay * by) + az * bz;
    return (sa_ + sb) - 2.0f * dt;
}

// ---------------- FPS large (N=32768, npoint=512): sorted chunks + register residency ----
// One 512-thread block per batch. Points bucket-sorted (8x8x8 over bbox) into SP as
// float4{x,y,z,bitcast(origidx)}. Thread t owns sorted positions [64t,64t+64): coords in
// VGPRs (fully unrolled), mind in LDS transposed mind[c*512+t] (stride-1 -> conflict-free).
// Per iter: thread skips when d2min(q, threadAABB) >= vb (its max mind) with conservative
// margin -- provable no-op. Global argmax: per-wave shfl reduce of (vb, orig, tid) + 8-entry
// scan; (value desc, orig asc) == reference first-occurrence argmax. Within-thread value
// ties tracked by flag, resolved on a cold block-uniform path (LDS atomicMin on packed
// (orig<<9|tid)). Winner coords broadcast via LDS; no dependent global read in the loop.

__global__ __launch_bounds__(512, 2) void fps_reg(const float* __restrict__ xyz,
                                                  int* __restrict__ inds,
                                                  float4* __restrict__ SPall) {
    const int b = blockIdx.x, t = threadIdx.x, w = t >> 6, l = t & 63;
    const float* __restrict__ P = xyz + (size_t)b * 32768 * 3;
    float4* __restrict__ SP = SPall + (size_t)b * 32768;

    __shared__ float mind[32768];              // slot = c*512 + t
    __shared__ float bxS[512], byS[512], bzS[512];
    __shared__ float candV[8];
    __shared__ int   candO[8];
    __shared__ int   candT[8];
    __shared__ float bbS[6];
    __shared__ float scr[48];
    __shared__ int   cntS[512], offS[512], curS[512];
    __shared__ int   tflagS;
    __shared__ unsigned tieKeyS;

    // ---- pass 1: per-batch bbox ----
    float mnx = 1e30f, mny = 1e30f, mnz = 1e30f;
    float mxx = -1e30f, mxy = -1e30f, mxz = -1e30f;
    for (int p = t; p < 32768; p += 512) {
        const float x = P[3 * p], y = P[3 * p + 1], z = P[3 * p + 2];
        mnx = fminf(mnx, x); mxx = fmaxf(mxx, x);
        mny = fminf(mny, y); mxy = fmaxf(mxy, y);
        mnz = fminf(mnz, z); mxz = fmaxf(mxz, z);
    }
#pragma unroll
    for (int o = 1; o < 64; o <<= 1) {
        mnx = fminf(mnx, __shfl_xor(mnx, o)); mxx = fmaxf(mxx, __shfl_xor(mxx, o));
        mny = fminf(mny, __shfl_xor(mny, o)); mxy = fmaxf(mxy, __shfl_xor(mxy, o));
        mnz = fminf(mnz, __shfl_xor(mnz, o)); mxz = fmaxf(mxz, __shfl_xor(mxz, o));
    }
    if (l == 0) {
        scr[w] = mnx; scr[8 + w] = mny; scr[16 + w] = mnz;
        scr[24 + w] = mxx; scr[32 + w] = mxy; scr[40 + w] = mxz;
    }
    __syncthreads();
    if (t == 0) {
        float a0 = 1e30f, a1 = 1e30f, a2 = 1e30f, a3 = -1e30f, a4 = -1e30f, a5 = -1e30f;
        for (int i = 0; i < 8; ++i) {
            a0 = fminf(a0, scr[i]);      a1 = fminf(a1, scr[8 + i]);
            a2 = fminf(a2, scr[16 + i]); a3 = fmaxf(a3, scr[24 + i]);
            a4 = fmaxf(a4, scr[32 + i]); a5 = fmaxf(a5, scr[40 + i]);
        }
        bbS[0] = a0; bbS[1] = a1; bbS[2] = a2; bbS[3] = a3; bbS[4] = a4; bbS[5] = a5;
        tflagS = 0; tieKeyS = 0xffffffffu;
    }
    __syncthreads();
    const float bx0 = bbS[0], by0 = bbS[1], bz0 = bbS[2];
    const float ex = bbS[3] - bx0, ey = bbS[4] - by0, ez = bbS[5] - bz0;
    const float ivx = ex > 1e-20f ? 8.0f / ex : 0.0f;
    const float ivy = ey > 1e-20f ? 8.0f / ey : 0.0f;
    const float ivz = ez > 1e-20f ? 8.0f / ez : 0.0f;

    // ---- pass 2: histogram ----
    cntS[t] = 0;
    __syncthreads();
    for (int p = t; p < 32768; p += 512) {
        const float x = P[3 * p], y = P[3 * p + 1], z = P[3 * p + 2];
        const int ix = min(7, (int)((x - bx0) * ivx));
        const int iy = min(7, (int)((y - by0) * ivy));
        const int iz = min(7, (int)((z - bz0) * ivz));
        atomicAdd(&cntS[(iz * 8 + iy) * 8 + ix], 1);
    }
    __syncthreads();

    // ---- exclusive scan ----
    offS[t] = cntS[t];
    __syncthreads();
    for (int d = 1; d < 512; d <<= 1) {
        const int v = (t >= d) ? offS[t - d] : 0;
        __syncthreads();
        offS[t] += v;
        __syncthreads();
    }
    const int myexc = offS[t] - cntS[t];
    curS[t] = myexc;
    __syncthreads();

    // ---- pass 3: scatter (recompute bucket) ----
    for (int p = t; p < 32768; p += 512) {
        const float x = P[3 * p], y = P[3 * p + 1], z = P[3 * p + 2];
        const int ix = min(7, (int)((x - bx0) * ivx));
        const int iy = min(7, (int)((y - by0) * ivy));
        const int iz = min(7, (int)((z - bz0) * ivz));
        const int pos = atomicAdd(&curS[(iz * 8 + iy) * 8 + ix], 1);
        SP[pos] = make_float4(x, y, z, __int_as_float(p));
    }
    __syncthreads();   // SP complete (same-CU L1 -> coherent within block)

    // ---- load own 64 sorted points into VGPRs; AABB; init mind ----
    float px[64], py[64], pz[64];
    float ax0 = 1e30f, ay0 = 1e30f, az0 = 1e30f;
    float ax1 = -1e30f, ay1 = -1e30f, az1 = -1e30f;
#pragma unroll
    for (int c = 0; c < 64; ++c) {
        const float4 f = SP[(size_t)t * 64 + c];
        px[c] = f.x; py[c] = f.y; pz[c] = f.z;
        ax0 = fminf(ax0, f.x); ax1 = fmaxf(ax1, f.x);
        ay0 = fminf(ay0, f.y); ay1 = fmaxf(ay1, f.y);
        az0 = fminf(az0, f.z); az1 = fmaxf(az1, f.z);
        mind[c * 512 + t] = 1e30f;
    }

    float vb = 1e30f;            // thread's max mind (forces act on first iter)
    int   orig = 0x7fffffff;     // orig idx of thread's best
    bool  tflag = false;         // within-thread value tie at vb
    float bx_t = 0.f, by_t = 0.f, bz_t = 0.f;
    float qx = P[0], qy = P[1], qz = P[2];
    if (t == 0) inds[b * 512] = 0;
    __syncthreads();

    for (int k = 1; k < 512; ++k) {
        // ---- phase A: prune or rescan own chunk ----
        const float ddx = fmaxf(fmaxf(ax0 - qx, qx - ax1), 0.0f);
        const float ddy = fmaxf(fmaxf(ay0 - qy, qy - ay1), 0.0f);
        const float ddz = fmaxf(fmaxf(az0 - qz, qz - az1), 0.0f);
        const float d2m = (ddx * ddx + ddy * ddy) + ddz * ddz;
        const bool act = d2m <= vb * 1.0001f + 1e-9f;
        if (act) {
            float nvb = -1.0f; int nbp = 0; bool nt = false;
#pragma unroll
            for (int c = 0; c < 64; ++c) {
                const float m = mind[c * 512 + t];
                const float d2 = sqd(px[c], py[c], pz[c], qx, qy, qz);
                const float nm = fminf(m, d2);
                mind[c * 512 + t] = nm;
                if (nm > nvb) { nvb = nm; nbp = c; nt = false;
                                bx_t = px[c]; by_t = py[c]; bz_t = pz[c]; }
                else if (nm == nvb) nt = true;
            }
            vb = nvb; tflag = nt;
            orig = __float_as_int(SP[(size_t)t * 64 + nbp].w);
            bxS[t] = bx_t; byS[t] = by_t; bzS[t] = bz_t;
        }
        // ---- wave reduce (value desc, orig asc) ----
        float v = vb; int o = orig; int ti = t;
#pragma unroll
        for (int s = 1; s < 64; s <<= 1) {
            const float ov = __shfl_xor(v, s);
            const int oo = __shfl_xor(o, s);
            const int ot = __shfl_xor(ti, s);
            if (ov > v || (ov == v && oo < o)) { v = ov; o = oo; ti = ot; }
        }
        if (l == 0) { candV[w] = v; candO[w] = o; candT[w] = ti; }
        __syncthreads();   // B1
        // ---- phase B: block winner ----
        float wv = candV[0]; int worig = candO[0], wtid = candT[0];
#pragma unroll
        for (int j = 1; j < 8; ++j) {
            const float v2 = candV[j]; const int o2 = candO[j], t2 = candT[j];
            if (v2 > wv || (v2 == wv && o2 < worig)) { wv = v2; worig = o2; wtid = t2; }
        }
        if (vb == wv && tflag) tflagS = 1;   // benign race (all write 1)
        float nqx = bxS[wtid], nqy = byS[wtid], nqz = bzS[wtid];
        __syncthreads();   // B2: tflagS visible; bxS/cand reads done before next writes
        if (tflagS) {      // cold path, block-uniform
            if (vb == wv) {
                unsigned mykey = 0xffffffffu;
                float tx = bx_t, ty = by_t, tz = bz_t;
#pragma unroll
                for (int c = 0; c < 64; ++c) {
                    if (mind[c * 512 + t] == wv) {
                        const int o3 = __float_as_int(SP[(size_t)t * 64 + c].w);
                        const unsigned kk = ((unsigned)o3 << 9) | (unsigned)t;
                        if (kk < mykey) { mykey = kk; tx = px[c]; ty = py[c]; tz = pz[c]; }
                    }
                }
                if (mykey != 0xffffffffu) {
                    atomicMin(&tieKeyS, mykey);
                    orig = (int)(mykey >> 9);
                    bx_t = tx; by_t = ty; bz_t = tz;
                    bxS[t] = tx; byS[t] = ty; bzS[t] = tz;
                }
            }
            __syncthreads();
            const unsigned wk = tieKeyS;
            worig = (int)(wk >> 9); wtid = (int)(wk & 511u);
            nqx = bxS[wtid]; nqy = byS[wtid]; nqz = bzS[wtid];
            __syncthreads();
            if (t == 0) { tflagS = 0; tieKeyS = 0xffffffffu; }
            __syncthreads();
        }
        if (t == 0) inds[b * 512 + k] = worig;   // fire-and-forget
        qx = nqx; qy = nqy; qz = nqz;
    }
}

// ---------------- FPS, small (N<=512), one wave per batch, all in registers ----------------

template <int N, int NPOINT>
__global__ __launch_bounds__(64) void fps_small(const float* __restrict__ pts,
                                                int* __restrict__ inds) {
    constexpr int PPT = N / 64;
    const int b = blockIdx.x, l = threadIdx.x;
    const float* __restrict__ P = pts + (size_t)b * N * 3;
    float px[PPT], py[PPT], pz[PPT], md[PPT];
#pragma unroll
    for (int j = 0; j < PPT; ++j) {
        const int p = l + 64 * j;
        px[j] = P[p * 3]; py[j] = P[p * 3 + 1]; pz[j] = P[p * 3 + 2];
        md[j] = 1e30f;
    }
    float qx = P[0], qy = P[1], qz = P[2];
    if (l == 0) inds[b * NPOINT] = 0;
    for (int k = 1; k < NPOINT; ++k) {
        float bv = -1.0f;
        int   bi = 0;
#pragma unroll
        for (int j = 0; j < PPT; ++j) {
            md[j] = fminf(md[j], sqd(px[j], py[j], pz[j], qx, qy, qz));
            if (md[j] > bv) { bv = md[j]; bi = l + 64 * j; }
        }
#pragma unroll
        for (int off = 1; off < 64; off <<= 1) {
            float ov = __shfl_xor(bv, off);
            int   oi = __shfl_xor(bi, off);
            if (ov > bv || (ov == bv && oi < bi)) { bv = ov; bi = oi; }
        }
        if (l == 0) inds[b * NPOINT + k] = bi;
        const int ol = bi & 63, js = bi >> 6;
        float sx = px[0], sy = py[0], sz = pz[0];
#pragma unroll
        for (int j = 1; j < PPT; ++j) {
            if (j == js) { sx = px[j]; sy = py[j]; sz = pz[j]; }
        }
        qx = __shfl(sx, ol); qy = __shfl(sy, ol); qz = __shfl(sz, ol);
    }
}

// ---------------- gather 3-float points by index ----------------

__global__ void gather3(const float* __restrict__ src, const int* __restrict__ inds,
                        float* __restrict__ dst, int Nsrc, int M, int total) {
    const int t = blockIdx.x * 256 + threadIdx.x;
    if (t >= total) return;
    const int b = t / M;
    const int n = inds[t];
    const float* s = src + ((size_t)b * Nsrc + n) * 3;
    float* d = dst + (size_t)t * 3;
    d[0] = s[0]; d[1] = s[1]; d[2] = s[2];
}

// ---------------- ball query: first NS points with d2 < r2, pad with first hit ----------------

template <int NS>
__global__ __launch_bounds__(256) void ball_query_k(const float* __restrict__ xyz,
                                                    const float* __restrict__ centers,
                                                    int* __restrict__ out,
                                                    int N, int M, float r2) {
    const int wv = blockIdx.x * 4 + (threadIdx.x >> 6);
    const int l  = threadIdx.x & 63;
    const int b  = wv / M;
    const float* cp = centers + (size_t)wv * 3;
    const float ax = cp[0], ay = cp[1], az = cp[2];
    const float sa_ = sum3sq(ax, ay, az);
    const float* __restrict__ P = xyz + (size_t)b * N * 3;
    int* o = out + (size_t)wv * NS;

    int cnt = 0, first = -1;
    float nx = P[l * 3], ny = P[l * 3 + 1], nz = P[l * 3 + 2];
    for (int i0 = 0; i0 < N; i0 += 64) {
        const float bx = nx, by = ny, bz = nz;
        if (i0 + 64 < N) {
            const int ip = (i0 + 64 + l) * 3;
            nx = P[ip]; ny = P[ip + 1]; nz = P[ip + 2];
        }
        const float d2 = sqd_dot(ax, ay, az, sa_, bx, by, bz);
        const bool in = d2 < r2;
        const unsigned long long mask = __ballot(in);
        if (first < 0 && mask != 0ull) first = i0 + __builtin_ctzll(mask);
        const int pos = cnt + __popcll(mask & ((1ull << l) - 1ull));
        if (in && pos < NS) o[pos] = i0 + l;
        cnt += __popcll(mask);
        if (cnt >= NS) break;
    }
    if (first < 0) first = 0;
    for (int p2 = cnt + l; p2 < NS; p2 += 64) o[p2] = first;
}

// ---------------- fused SA for sa1: gather + normalize + 3-layer MLP + max ----------------

template <int NS, int CF, int C1, int C2, int C3>
__global__ __launch_bounds__(64) void sa_fused(
    const float* __restrict__ xyz, const float* __restrict__ feats,
    const float* __restrict__ centers, const int* __restrict__ idx,
    const float* __restrict__ w0, const float* __restrict__ b0,
    const float* __restrict__ w1, const float* __restrict__ b1,
    const float* __restrict__ w2, const float* __restrict__ b2,
    float* __restrict__ outf, int N, int M, float r) {
    constexpr int CIN = 3 + CF;
    constexpr int CL  = (C3 > 0) ? C3 : C2;
    constexpr int CPB = 64 / NS;
    const int tid = threadIdx.x;
    const int ci = tid / NS, s = tid % NS;
    const int gc = blockIdx.x * CPB + ci;
    const int b  = gc / M;
    const float* cp = centers + (size_t)gc * 3;
    const float cx = cp[0], cy = cp[1], cz = cp[2];
    const int n = idx[(size_t)gc * NS + s];
    const float* pp = xyz + ((size_t)b * N + n) * 3;
    float gi[CIN];
    gi[0] = (pp[0] - cx) / r; gi[1] = (pp[1] - cy) / r; gi[2] = (pp[2] - cz) / r;
    if constexpr (CF > 0) {
        const float* fr = feats + ((size_t)b * N + n) * CF;
#pragma unroll
        for (int c = 0; c < CF; ++c) gi[3 + c] = fr[c];
    }
    float h1[C1];
#pragma unroll
    for (int o = 0; o < C1; ++o) {
        float acc = b0[o];
#pragma unroll
        for (int k = 0; k < CIN; ++k) acc += gi[k] * w0[k * C1 + o];
        h1[o] = fmaxf(acc, 0.f);
    }
    float h2[C2];
#pragma unroll
    for (int o = 0; o < C2; ++o) {
        float acc = b1[o];
#pragma unroll
        for (int k = 0; k < C1; ++k) acc += h1[k] * w1[k * C2 + o];
        h2[o] = fmaxf(acc, 0.f);
    }
    float hl[CL];
    if constexpr (C3 > 0) {
#pragma unroll
        for (int o = 0; o < C3; ++o) {
            float acc = b2[o];
#pragma unroll
            for (int k = 0; k < C2; ++k) acc += h2[k] * w2[k * C3 + o];
            hl[o] = fmaxf(acc, 0.f);
        }
    } else {
#pragma unroll
        for (int o = 0; o < CL; ++o) hl[o] = h2[o];
    }
    __shared__ float hs[64][CL + 1];
#pragma unroll
    for (int c = 0; c < CL; ++c) hs[tid][c] = hl[c];
    __syncthreads();
    for (int cc = 0; cc < CPB; ++cc) {
        for (int c = tid; c < CL; c += 64) {
            float mx = hs[cc * NS][c];
            for (int s2 = 1; s2 < NS; ++s2) mx = fmaxf(mx, hs[cc * NS + s2][c]);
            outf[(size_t)(blockIdx.x * CPB + cc) * CL + c] = mx;
        }
    }
}

// ---------------- build grouped input rows: [(p-c)/r | feats[n]] ----------------

__global__ void build_g(const float* __restrict__ xyz, const float* __restrict__ feats,
                        const float* __restrict__ centers, const int* __restrict__ idx,
                        float* __restrict__ g, int N, int M, int NS, int CF, float r) {
    const int row = blockIdx.x * 4 + (threadIdx.x >> 6);
    const int l   = threadIdx.x & 63;
    const int gc  = row / NS;
    const int b   = gc / M;
    const int n   = idx[row];
    const float* cp = centers + (size_t)gc * 3;
    const float* pp = xyz + ((size_t)b * N + n) * 3;
    float* go = g + (size_t)row * (3 + CF);
    if (l < 3) go[l] = (pp[l] - cp[l]) / r;
    for (int c = l; c < CF; c += 64) go[3 + c] = feats[((size_t)b * N + n) * CF + c];
}

// ---------------- dense layer + relu ----------------

__global__ void dense_relu(const float* __restrict__ X, const float* __restrict__ Wm,
                           const float* __restrict__ bias, float* __restrict__ Y,
                           int M, int CI, int CO) {
    const int co = blockIdx.x * 64 + threadIdx.x;
    const int m  = blockIdx.y * 4 + threadIdx.y;
    const float* x = X + (size_t)m * CI;
    float acc = bias[co];
#pragma unroll 4
    for (int k = 0; k < CI; ++k) acc += x[k] * Wm[(size_t)k * CO + co];
    Y[(size_t)m * CO + co] = fmaxf(acc, 0.f);
}

// ---------------- max over samples ----------------

__global__ void max_ns(const float* __restrict__ H, float* __restrict__ F,
                       int BM, int NS, int C) {
    const int tid = blockIdx.x * 256 + threadIdx.x;
    if (tid >= BM * C) return;
    const int bm = tid / C, c = tid % C;
    const float* h = H + ((size_t)bm * NS) * C + c;
    float mx = h[0];
    for (int s = 1; s < NS; ++s) mx = fmaxf(mx, h[(size_t)s * C]);
    F[tid] = mx;
}

// ---------------- FP: 3-NN + inverse-distance weights ----------------

__global__ void fp_nn(const float* __restrict__ unk, const float* __restrict__ kn,
                      int* __restrict__ nni, float* __restrict__ nnw, int NU, int NK) {
    const int t = blockIdx.x * blockDim.x + threadIdx.x;
    const int b = t / NU;
    const float* u = unk + (size_t)t * 3;
    const float ax = u[0], ay = u[1], az = u[2];
    const float sa_ = sum3sq(ax, ay, az);
    const float* K = kn + (size_t)b * NK * 3;
    float v0 = 1e30f, v1 = 1e30f, v2 = 1e30f;
    int   j0 = 0, j1 = 0, j2 = 0;
    for (int k = 0; k < NK; ++k) {
        const float d2 = sqd_dot(ax, ay, az, sa_, K[k * 3], K[k * 3 + 1], K[k * 3 + 2]);
        if (d2 < v0)      { v2 = v1; j2 = j1; v1 = v0; j1 = j0; v0 = d2; j0 = k; }
        else if (d2 < v1) { v2 = v1; j2 = j1; v1 = d2; j1 = k; }
        else if (d2 < v2) { v2 = d2; j2 = k; }
    }
    const float d0 = fmaxf(v0, 0.f), d1 = fmaxf(v1, 0.f), dd2 = fmaxf(v2, 0.f);
    float w0 = 1.f / (d0 + 1e-8f), w1 = 1.f / (d1 + 1e-8f), w2 = 1.f / (dd2 + 1e-8f);
    const float s = (w0 + w1) + w2;
    nnw[t * 3] = w0 / s; nnw[t * 3 + 1] = w1 / s; nnw[t * 3 + 2] = w2 / s;
    nni[t * 3] = j0; nni[t * 3 + 1] = j1; nni[t * 3 + 2] = j2;
}

// ---------------- FP: concat [feats1 | interp(feats2)] ----------------

__global__ void interp_concat(const float* __restrict__ f1, const float* __restrict__ f2,
                              const int* __restrict__ nni, const float* __restrict__ nnw,
                              float* __restrict__ X, int NU, int NK, int C1c, int C2c) {
    const int row = blockIdx.x * 4 + (threadIdx.x >> 6);
    const int l   = threadIdx.x & 63;
    const int b   = row / NU;
    const int i0 = nni[row * 3], i1 = nni[row * 3 + 1], i2 = nni[row * 3 + 2];
    const float w0 = nnw[row * 3], w1 = nnw[row * 3 + 1], w2 = nnw[row * 3 + 2];
    float* xo = X + (size_t)row * (C1c + C2c);
    for (int c = l; c < C1c; c += 64) xo[c] = f1[(size_t)row * C1c + c];
    const float* a  = f2 + ((size_t)b * NK + i0) * C2c;
    const float* bb = f2 + ((size_t)b * NK + i1) * C2c;
    const float* cc = f2 + ((size_t)b * NK + i2) * C2c;
    for (int c = l; c < C2c; c += 64) xo[C1c + c] = (w0 * a[c] + w1 * bb[c]) + w2 * cc[c];
}

__global__ void copyf(const float* __restrict__ src, float* __restrict__ dst, int n) {
    const int i = blockIdx.x * 256 + threadIdx.x;
    if (i < n) dst[i] = src[i];
}

// ---------------- host launcher ----------------

extern "C" void kernel_launch(void* const* d_in, const int* in_sizes, int n_in,
                              void* d_out, int out_size, void* d_ws, size_t ws_size,
                              hipStream_t stream) {
    const float* xyz  = (const float*)d_in[0];
    const float* s1w0 = (const float*)d_in[1],  *s1b0 = (const float*)d_in[2];
    const float* s1w1 = (const float*)d_in[3],  *s1b1 = (const float*)d_in[4];
    const float* s1w2 = (const float*)d_in[5],  *s1b2 = (const float*)d_in[6];
    const float* s2w0 = (const float*)d_in[7],  *s2b0 = (const float*)d_in[8];
    const float* s2w1 = (const float*)d_in[9],  *s2b1 = (const float*)d_in[10];
    const float* s3w0 = (const float*)d_in[11], *s3b0 = (const float*)d_in[12];
    const float* s3w1 = (const float*)d_in[13], *s3b1 = (const float*)d_in[14];
    const float* s4w0 = (const float*)d_in[15], *s4b0 = (const float*)d_in[16];
    const float* s4w1 = (const float*)d_in[17], *s4b1 = (const float*)d_in[18];
    const float* p1w0 = (const float*)d_in[19], *p1b0 = (const float*)d_in[20];
    const float* p1w1 = (const float*)d_in[21], *p1b1 = (const float*)d_in[22];
    const float* p2w0 = (const float*)d_in[23], *p2b0 = (const float*)d_in[24];
    const float* p2w1 = (const float*)d_in[25], *p2b1 = (const float*)d_in[26];
    float* out = (float*)d_out;
    float* W = (float*)d_ws;

    size_t off = 0;
    auto A_ = [&](size_t n) { size_t o = off; off += (n + 63) & ~(size_t)63; return o; };
    const size_t o_inds1 = A_(4 * 512);
    const size_t o_xyz1  = A_(4 * 512 * 3);
    const size_t o_idx1  = A_(4 * 512 * 64);
    const size_t o_f1    = A_(4 * 512 * 64);
    const size_t o_inds2 = A_(4 * 256);
    const size_t o_xyz2  = A_(4 * 256 * 3);
    const size_t o_idx2  = A_(4 * 256 * 32);
    const size_t o_f2    = A_(4 * 256 * 128);
    const size_t o_inds3 = A_(4 * 64);
    const size_t o_xyz3  = A_(4 * 64 * 3);
    const size_t o_idx3  = A_(4 * 64 * 16);
    const size_t o_f3    = A_(4 * 64 * 256);
    const size_t o_inds4 = A_(4 * 16);
    const size_t o_xyz4  = A_(4 * 16 * 3);
    const size_t o_idx4  = A_(4 * 16 * 16);
    const size_t o_f4    = A_(4 * 16 * 256);
    const size_t o_f5    = A_(4 * 64 * 128);
    const size_t o_nni1  = A_(4 * 64 * 3);
    const size_t o_nnw1  = A_(4 * 64 * 3);
    const size_t o_nni2  = A_(4 * 256 * 3);
    const size_t o_nnw2  = A_(4 * 256 * 3);
    const size_t o_sort  = A_((size_t)4 * 32768 * 4);  // float4 sorted points
    const size_t o_bufA  = A_((size_t)32768 * 128);    // 16 MiB arena
    const size_t o_bufB  = A_((size_t)32768 * 64);     //  8 MiB arena
    if (off * sizeof(float) > ws_size) return;  // fail loudly (validation will catch)

    int*   inds1 = (int*)(W + o_inds1); float* xyz1 = W + o_xyz1;
    int*   idx1  = (int*)(W + o_idx1);  float* f1   = W + o_f1;
    int*   inds2 = (int*)(W + o_inds2); float* xyz2 = W + o_xyz2;
    int*   idx2  = (int*)(W + o_idx2);  float* f2   = W + o_f2;
    int*   inds3 = (int*)(W + o_inds3); float* xyz3 = W + o_xyz3;
    int*   idx3  = (int*)(W + o_idx3);  float* f3   = W + o_f3;
    int*   inds4 = (int*)(W + o_inds4); float* xyz4 = W + o_xyz4;
    int*   idx4  = (int*)(W + o_idx4);  float* f4   = W + o_f4;
    float* f5    = W + o_f5;
    int*   nni1  = (int*)(W + o_nni1);  float* nnw1 = W + o_nnw1;
    int*   nni2  = (int*)(W + o_nni2);  float* nnw2 = W + o_nnw2;
    float4* sortP = (float4*)(W + o_sort);
    float* bufA  = W + o_bufA;
    float* bufB  = W + o_bufB;

    // -------- sa1: npoint=512, r=0.1, ns=64, MLP 3->32->32->64 --------
    fps_reg<<<4, 512, 0, stream>>>(xyz, inds1, sortP);
    gather3<<<8, 256, 0, stream>>>(xyz, inds1, xyz1, 32768, 512, 2048);
    ball_query_k<64><<<512, 256, 0, stream>>>(xyz, xyz1, idx1, 32768, 512, (float)(0.1 * 0.1));
    sa_fused<64, 0, 32, 32, 64><<<2048, 64, 0, stream>>>(
        xyz, nullptr, xyz1, idx1, s1w0, s1b0, s1w1, s1b1, s1w2, s1b2, f1, 32768, 512, 0.1f);

    // -------- sa2: npoint=256, r=0.2, ns=32, MLP 67->64->128 --------
    fps_small<512, 256><<<4, 64, 0, stream>>>(xyz1, inds2);
    gather3<<<4, 256, 0, stream>>>(xyz1, inds2, xyz2, 512, 256, 1024);
    ball_query_k<32><<<256, 256, 0, stream>>>(xyz1, xyz2, idx2, 512, 256, (float)(0.2 * 0.2));
    build_g<<<32768 / 4, 256, 0, stream>>>(xyz1, f1, xyz2, idx2, bufA, 512, 256, 32, 64, 0.2f);
    dense_relu<<<dim3(1, 32768 / 4), dim3(64, 4), 0, stream>>>(bufA, s2w0, s2b0, bufB, 32768, 67, 64);
    dense_relu<<<dim3(2, 32768 / 4), dim3(64, 4), 0, stream>>>(bufB, s2w1, s2b1, bufA, 32768, 64, 128);
    max_ns<<<(1024 * 128 + 255) / 256, 256, 0, stream>>>(bufA, f2, 1024, 32, 128);

    // -------- sa3: npoint=64, r=0.4, ns=16, MLP 131->128->256 --------
    fps_small<256, 64><<<4, 64, 0, stream>>>(xyz2, inds3);
    gather3<<<1, 256, 0, stream>>>(xyz2, inds3, xyz3, 256, 64, 256);
    ball_query_k<16><<<64, 256, 0, stream>>>(xyz2, xyz3, idx3, 256, 64, (float)(0.4 * 0.4));
    build_g<<<4096 / 4, 256, 0, stream>>>(xyz2, f2, xyz3, idx3, bufA, 256, 64, 16, 128, 0.4f);
    dense_relu<<<dim3(2, 4096 / 4), dim3(64, 4), 0, stream>>>(bufA, s3w0, s3b0, bufB, 4096, 131, 128);
    dense_relu<<<dim3(4, 4096 / 4), dim3(64, 4), 0, stream>>>(bufB, s3w1, s3b1, bufA, 4096, 128, 256);
    max_ns<<<(256 * 256 + 255) / 256, 256, 0, stream>>>(bufA, f3, 256, 16, 256);

    // -------- sa4: npoint=16, r=0.8, ns=16, MLP 259->256->256 --------
    fps_small<64, 16><<<4, 64, 0, stream>>>(xyz3, inds4);
    gather3<<<1, 256, 0, stream>>>(xyz3, inds4, xyz4, 64, 16, 64);
    ball_query_k<16><<<16, 256, 0, stream>>>(xyz3, xyz4, idx4, 64, 16, (float)(0.8 * 0.8));
    build_g<<<1024 / 4, 256, 0, stream>>>(xyz3, f3, xyz4, idx4, bufA, 64, 16, 16, 256, 0.8f);
    dense_relu<<<dim3(4, 1024 / 4), dim3(64, 4), 0, stream>>>(bufA, s4w0, s4b0, bufB, 1024, 259, 256);
    dense_relu<<<dim3(4, 1024 / 4), dim3(64, 4), 0, stream>>>(bufB, s4w1, s4b1, bufA, 1024, 256, 256);
    max_ns<<<(64 * 256 + 255) / 256, 256, 0, stream>>>(bufA, f4, 64, 16, 256);

    // -------- fp1: xyz3 <- xyz4, [f3 | interp(f4)] 512->256->128 --------
    fp_nn<<<1, 256, 0, stream>>>(xyz3, xyz4, nni1, nnw1, 64, 16);
    interp_concat<<<256 / 4, 256, 0, stream>>>(f3, f4, nni1, nnw1, bufA, 64, 16, 256, 256);
    dense_relu<<<dim3(4, 256 / 4), dim3(64, 4), 0, stream>>>(bufA, p1w0, p1b0, bufB, 256, 512, 256);
    dense_relu<<<dim3(2, 256 / 4), dim3(64, 4), 0, stream>>>(bufB, p1w1, p1b1, f5, 256, 256, 128);

    // -------- fp2: xyz2 <- xyz3, [f2 | interp(f5)] 256->128->64 --------
    fp_nn<<<4, 256, 0, stream>>>(xyz2, xyz3, nni2, nnw2, 256, 64);
    interp_concat<<<1024 / 4, 256, 0, stream>>>(f2, f5, nni2, nnw2, bufA, 256, 64, 128, 128);
    dense_relu<<<dim3(2, 1024 / 4), dim3(64, 4), 0, stream>>>(bufA, p2w0, p2b0, bufB, 1024, 256, 128);
    dense_relu<<<dim3(1, 1024 / 4), dim3(64, 4), 0, stream>>>(bufB, p2w1, p2b1, out, 1024, 128, 64);

    // -------- outputs: [f (4x256x64) | xyz2 (4x256x3)] --------
    copyf<<<12, 256, 0, stream>>>(xyz2, out + 65536, 3072);
}

// Round 5
// 3361.305 us; speedup vs baseline: 2.4442x; 2.0805x over previous
//
#include <hip/hip_runtime.h>
#include <cstddef>

// ---------------- numerics helpers (mirror reference FP32 op order) ----------------

__device__ __forceinline__ float sqd(float x, float y, float z, float qx, float qy, float qz) {
#pragma clang fp contract(off)
    float dx = x - qx, dy = y - qy, dz = z - qz;
    return (dx * dx + dy * dy) + dz * dz;
}

__device__ __forceinline__ float sum3sq(float x, float y, float z) {
#pragma clang fp contract(off)
    return (x * x + y * y) + z * z;
}

// reference _sqdist: sum(a^2) + sum(b^2) - 2*dot(a,b)
__device__ __forceinline__ float sqd_dot(float ax, float ay, float az, float sa_,
                                         float bx, float by, float bz) {
#pragma clang fp contract(off)
    float sb = (bx * bx + by * by) + bz * bz;
    float dt = (ax * bx + ay * by) + az * bz;
    return (sa_ + sb) - 2.0f * dt;
}

// ---------------- FPS large (N=32768, npoint=512): bucketed pruning + shared work queue --
// One 512-thread block per batch. Points bucket-sorted (8x8x8 grid over per-batch bbox)
// into SP as float4{x,y,z,bitcast(origidx)}; mind[] in LDS in sorted order (contiguous,
// 2-way bank aliasing = free). Per iteration:
//   (1) thread t tests bucket t: skip when d2min(q, cell box) >= cached bmax (provable
//       fminf no-op, conservative margin); active -> push t into LDS queue.
//   (2) all 8 waves pull queue entries round-robin (load-balanced, parallel buckets):
//       64 lanes scan the bucket cooperatively (coalesced SP float4 + contiguous mind),
//       reduce (val desc, orig asc) + winner coords via shfl; lane0 refreshes the
//       per-bucket cache (bmaxS, bargS, bxyzS).
//   (3) block argmax over 512 cached buckets; winner coords read from LDS (no dependent
//       global read on the critical path). Ordering (val desc, orig asc) everywhere ==
//       reference first-occurrence argmax; caches stay exact for pruned buckets since
//       their mind values provably unchanged. 3 barriers/iter.

__global__ __launch_bounds__(512) void fps_queue(const float* __restrict__ xyz,
                                                 int* __restrict__ inds,
                                                 float4* __restrict__ SPall) {
    const int b = blockIdx.x, t = threadIdx.x, w = t >> 6, l = t & 63;
    const float* __restrict__ P = xyz + (size_t)b * 32768 * 3;
    float4* __restrict__ SP = SPall + (size_t)b * 32768;

    __shared__ float mind[32768];
    __shared__ int   cntS[512], offS[512], curS[512];   // curS reused as the work queue
    __shared__ float bmaxS[512];
    __shared__ int   bargS[512];
    __shared__ float bxS[512], byS[512], bzS[512];
    __shared__ float candV[8];
    __shared__ int   candO[8], candB[8];
    __shared__ float bbS[6];
    __shared__ float scr[48];
    __shared__ int   qcntS;

    // ---- pass 1: per-batch bbox ----
    float mnx = 1e30f, mny = 1e30f, mnz = 1e30f;
    float mxx = -1e30f, mxy = -1e30f, mxz = -1e30f;
    for (int p = t; p < 32768; p += 512) {
        const float x = P[3 * p], y = P[3 * p + 1], z = P[3 * p + 2];
        mnx = fminf(mnx, x); mxx = fmaxf(mxx, x);
        mny = fminf(mny, y); mxy = fmaxf(mxy, y);
        mnz = fminf(mnz, z); mxz = fmaxf(mxz, z);
    }
#pragma unroll
    for (int o = 1; o < 64; o <<= 1) {
        mnx = fminf(mnx, __shfl_xor(mnx, o)); mxx = fmaxf(mxx, __shfl_xor(mxx, o));
        mny = fminf(mny, __shfl_xor(mny, o)); mxy = fmaxf(mxy, __shfl_xor(mxy, o));
        mnz = fminf(mnz, __shfl_xor(mnz, o)); mxz = fmaxf(mxz, __shfl_xor(mxz, o));
    }
    if (l == 0) {
        scr[w] = mnx; scr[8 + w] = mny; scr[16 + w] = mnz;
        scr[24 + w] = mxx; scr[32 + w] = mxy; scr[40 + w] = mxz;
    }
    __syncthreads();
    if (t == 0) {
        float a0 = 1e30f, a1 = 1e30f, a2 = 1e30f, a3 = -1e30f, a4 = -1e30f, a5 = -1e30f;
        for (int i = 0; i < 8; ++i) {
            a0 = fminf(a0, scr[i]);      a1 = fminf(a1, scr[8 + i]);
            a2 = fminf(a2, scr[16 + i]); a3 = fmaxf(a3, scr[24 + i]);
            a4 = fmaxf(a4, scr[32 + i]); a5 = fmaxf(a5, scr[40 + i]);
        }
        bbS[0] = a0; bbS[1] = a1; bbS[2] = a2; bbS[3] = a3; bbS[4] = a4; bbS[5] = a5;
        qcntS = 0;
    }
    __syncthreads();
    const float bx0 = bbS[0], by0 = bbS[1], bz0 = bbS[2];
    const float ex = bbS[3] - bx0, ey = bbS[4] - by0, ez = bbS[5] - bz0;
    const float ivx = ex > 1e-20f ? 8.0f / ex : 0.0f;
    const float ivy = ey > 1e-20f ? 8.0f / ey : 0.0f;
    const float ivz = ez > 1e-20f ? 8.0f / ez : 0.0f;

    // ---- pass 2: histogram ----
    cntS[t] = 0;
    __syncthreads();
    for (int p = t; p < 32768; p += 512) {
        const float x = P[3 * p], y = P[3 * p + 1], z = P[3 * p + 2];
        const int ix = min(7, (int)((x - bx0) * ivx));
        const int iy = min(7, (int)((y - by0) * ivy));
        const int iz = min(7, (int)((z - bz0) * ivz));
        atomicAdd(&cntS[(iz * 8 + iy) * 8 + ix], 1);
    }
    __syncthreads();

    // ---- exclusive scan (Hillis-Steele over 512) ----
    offS[t] = cntS[t];
    __syncthreads();
    for (int d = 1; d < 512; d <<= 1) {
        const int v = (t >= d) ? offS[t - d] : 0;
        __syncthreads();
        offS[t] += v;
        __syncthreads();
    }
    const int myexc = offS[t] - cntS[t];
    offS[t] = myexc;
    curS[t] = myexc;
    __syncthreads();

    // ---- pass 3: scatter ----
    for (int p = t; p < 32768; p += 512) {
        const float x = P[3 * p], y = P[3 * p + 1], z = P[3 * p + 2];
        const int ix = min(7, (int)((x - bx0) * ivx));
        const int iy = min(7, (int)((y - by0) * ivy));
        const int iz = min(7, (int)((z - bz0) * ivz));
        const int pos = atomicAdd(&curS[(iz * 8 + iy) * 8 + ix], 1);
        SP[pos] = make_float4(x, y, z, __int_as_float(p));
    }
    // ---- init mind + per-bucket caches ----
    for (int s = t; s < 32768; s += 512) mind[s] = 1e30f;
    const int myCnt = cntS[t];
    bmaxS[t] = (myCnt > 0) ? 1e30f : -1.0f;
    bargS[t] = 0x7fffffff;
    bxS[t] = 0.f; byS[t] = 0.f; bzS[t] = 0.f;
    if (t == 0) inds[b * 512] = 0;

    // per-thread cell box (registers only; tiny state -> no spills)
    const int oix = t & 7, oiy = (t >> 3) & 7, oiz = t >> 6;
    const float gwx = ex * 0.125f, gwy = ey * 0.125f, gwz = ez * 0.125f;
    const float x0o = bx0 + oix * gwx, x1o = x0o + gwx;
    const float y0o = by0 + oiy * gwy, y1o = y0o + gwy;
    const float z0o = bz0 + oiz * gwz, z1o = z0o + gwz;

    float qx = P[0], qy = P[1], qz = P[2];
    __syncthreads();   // SP + mind + caches ready

    for (int k = 1; k < 512; ++k) {
        // ---- (1) test own bucket, push to queue ----
        const float ddx = fmaxf(fmaxf(x0o - qx, qx - x1o), 0.0f);
        const float ddy = fmaxf(fmaxf(y0o - qy, qy - y1o), 0.0f);
        const float ddz = fmaxf(fmaxf(z0o - qz, qz - z1o), 0.0f);
        const float d2m = (ddx * ddx + ddy * ddy) + ddz * ddz;
        const float bm = bmaxS[t];
        if (myCnt > 0 && d2m <= bm * 1.0001f + 1e-9f) {
            const int slot = atomicAdd(&qcntS, 1);
            curS[slot] = t;
        }
        __syncthreads();   // B1: queue complete
        const int A = qcntS;

        // ---- (2) process queue entries, wave-strided ----
        for (int e = w; e < A; e += 8) {
            const int bu = curS[e];
            const int base = offS[bu], cnt = cntS[bu];
            float vb = -1.0f; int ib = 0x7fffffff;
            float cx = 0.f, cy = 0.f, cz = 0.f;
            for (int c = l; c < cnt; c += 64) {
                const float4 pt = SP[base + c];
                const float m = mind[base + c];
                const float d2 = sqd(pt.x, pt.y, pt.z, qx, qy, qz);
                const float nm = fminf(m, d2);
                mind[base + c] = nm;
                const int oi = __float_as_int(pt.w);
                if (nm > vb || (nm == vb && oi < ib)) {
                    vb = nm; ib = oi; cx = pt.x; cy = pt.y; cz = pt.z;
                }
            }
            int lb = l;
#pragma unroll
            for (int s = 1; s < 64; s <<= 1) {
                const float ov = __shfl_xor(vb, s);
                const int oo = __shfl_xor(ib, s);
                const int ol2 = __shfl_xor(lb, s);
                if (ov > vb || (ov == vb && oo < ib)) { vb = ov; ib = oo; lb = ol2; }
            }
            const float wx = __shfl(cx, lb), wy = __shfl(cy, lb), wz = __shfl(cz, lb);
            if (l == 0) {
                bmaxS[bu] = vb; bargS[bu] = ib;
                bxS[bu] = wx; byS[bu] = wy; bzS[bu] = wz;
            }
        }
        __syncthreads();   // B2: caches refreshed

        // ---- (3) block argmax over 512 cached buckets ----
        float v = bmaxS[t]; int o = bargS[t]; int bu2 = t;
#pragma unroll
        for (int s = 1; s < 64; s <<= 1) {
            const float ov = __shfl_xor(v, s);
            const int oo = __shfl_xor(o, s);
            const int ob = __shfl_xor(bu2, s);
            if (ov > v || (ov == v && oo < o)) { v = ov; o = oo; bu2 = ob; }
        }
        if (l == 0) { candV[w] = v; candO[w] = o; candB[w] = bu2; }
        if (t == 0) qcntS = 0;
        __syncthreads();   // B3: candidates visible, queue reset
        float wv = candV[0]; int wo = candO[0], wb = candB[0];
#pragma unroll
        for (int j = 1; j < 8; ++j) {
            const float v2 = candV[j]; const int o2 = candO[j], b2 = candB[j];
            if (v2 > wv || (v2 == wv && o2 < wo)) { wv = v2; wo = o2; wb = b2; }
        }
        if (t == 0) inds[b * 512 + k] = wo;   // fire-and-forget
        qx = bxS[wb]; qy = byS[wb]; qz = bzS[wb];
        // reads of bxS/cand complete before any thread passes next B1 -> safe
    }
}

// ---------------- FPS, small (N<=512), one wave per batch, all in registers ----------------

template <int N, int NPOINT>
__global__ __launch_bounds__(64) void fps_small(const float* __restrict__ pts,
                                                int* __restrict__ inds) {
    constexpr int PPT = N / 64;
    const int b = blockIdx.x, l = threadIdx.x;
    const float* __restrict__ P = pts + (size_t)b * N * 3;
    float px[PPT], py[PPT], pz[PPT], md[PPT];
#pragma unroll
    for (int j = 0; j < PPT; ++j) {
        const int p = l + 64 * j;
        px[j] = P[p * 3]; py[j] = P[p * 3 + 1]; pz[j] = P[p * 3 + 2];
        md[j] = 1e30f;
    }
    float qx = P[0], qy = P[1], qz = P[2];
    if (l == 0) inds[b * NPOINT] = 0;
    for (int k = 1; k < NPOINT; ++k) {
        float bv = -1.0f;
        int   bi = 0;
#pragma unroll
        for (int j = 0; j < PPT; ++j) {
            md[j] = fminf(md[j], sqd(px[j], py[j], pz[j], qx, qy, qz));
            if (md[j] > bv) { bv = md[j]; bi = l + 64 * j; }
        }
#pragma unroll
        for (int off = 1; off < 64; off <<= 1) {
            float ov = __shfl_xor(bv, off);
            int   oi = __shfl_xor(bi, off);
            if (ov > bv || (ov == bv && oi < bi)) { bv = ov; bi = oi; }
        }
        if (l == 0) inds[b * NPOINT + k] = bi;
        const int ol = bi & 63, js = bi >> 6;
        float sx = px[0], sy = py[0], sz = pz[0];
#pragma unroll
        for (int j = 1; j < PPT; ++j) {
            if (j == js) { sx = px[j]; sy = py[j]; sz = pz[j]; }
        }
        qx = __shfl(sx, ol); qy = __shfl(sy, ol); qz = __shfl(sz, ol);
    }
}

// ---------------- gather 3-float points by index ----------------

__global__ void gather3(const float* __restrict__ src, const int* __restrict__ inds,
                        float* __restrict__ dst, int Nsrc, int M, int total) {
    const int t = blockIdx.x * 256 + threadIdx.x;
    if (t >= total) return;
    const int b = t / M;
    const int n = inds[t];
    const float* s = src + ((size_t)b * Nsrc + n) * 3;
    float* d = dst + (size_t)t * 3;
    d[0] = s[0]; d[1] = s[1]; d[2] = s[2];
}

// ---------------- ball query: first NS points with d2 < r2, pad with first hit ----------------

template <int NS>
__global__ __launch_bounds__(256) void ball_query_k(const float* __restrict__ xyz,
                                                    const float* __restrict__ centers,
                                                    int* __restrict__ out,
                                                    int N, int M, float r2) {
    const int wv = blockIdx.x * 4 + (threadIdx.x >> 6);
    const int l  = threadIdx.x & 63;
    const int b  = wv / M;
    const float* cp = centers + (size_t)wv * 3;
    const float ax = cp[0], ay = cp[1], az = cp[2];
    const float sa_ = sum3sq(ax, ay, az);
    const float* __restrict__ P = xyz + (size_t)b * N * 3;
    int* o = out + (size_t)wv * NS;

    int cnt = 0, first = -1;
    float nx = P[l * 3], ny = P[l * 3 + 1], nz = P[l * 3 + 2];
    for (int i0 = 0; i0 < N; i0 += 64) {
        const float bx = nx, by = ny, bz = nz;
        if (i0 + 64 < N) {
            const int ip = (i0 + 64 + l) * 3;
            nx = P[ip]; ny = P[ip + 1]; nz = P[ip + 2];
        }
        const float d2 = sqd_dot(ax, ay, az, sa_, bx, by, bz);
        const bool in = d2 < r2;
        const unsigned long long mask = __ballot(in);
        if (first < 0 && mask != 0ull) first = i0 + __builtin_ctzll(mask);
        const int pos = cnt + __popcll(mask & ((1ull << l) - 1ull));
        if (in && pos < NS) o[pos] = i0 + l;
        cnt += __popcll(mask);
        if (cnt >= NS) break;
    }
    if (first < 0) first = 0;
    for (int p2 = cnt + l; p2 < NS; p2 += 64) o[p2] = first;
}

// ---------------- fused SA for sa1: gather + normalize + 3-layer MLP + max ----------------

template <int NS, int CF, int C1, int C2, int C3>
__global__ __launch_bounds__(64) void sa_fused(
    const float* __restrict__ xyz, const float* __restrict__ feats,
    const float* __restrict__ centers, const int* __restrict__ idx,
    const float* __restrict__ w0, const float* __restrict__ b0,
    const float* __restrict__ w1, const float* __restrict__ b1,
    const float* __restrict__ w2, const float* __restrict__ b2,
    float* __restrict__ outf, int N, int M, float r) {
    constexpr int CIN = 3 + CF;
    constexpr int CL  = (C3 > 0) ? C3 : C2;
    constexpr int CPB = 64 / NS;
    const int tid = threadIdx.x;
    const int ci = tid / NS, s = tid % NS;
    const int gc = blockIdx.x * CPB + ci;
    const int b  = gc / M;
    const float* cp = centers + (size_t)gc * 3;
    const float cx = cp[0], cy = cp[1], cz = cp[2];
    const int n = idx[(size_t)gc * NS + s];
    const float* pp = xyz + ((size_t)b * N + n) * 3;
    float gi[CIN];
    gi[0] = (pp[0] - cx) / r; gi[1] = (pp[1] - cy) / r; gi[2] = (pp[2] - cz) / r;
    if constexpr (CF > 0) {
        const float* fr = feats + ((size_t)b * N + n) * CF;
#pragma unroll
        for (int c = 0; c < CF; ++c) gi[3 + c] = fr[c];
    }
    float h1[C1];
#pragma unroll
    for (int o = 0; o < C1; ++o) {
        float acc = b0[o];
#pragma unroll
        for (int k = 0; k < CIN; ++k) acc += gi[k] * w0[k * C1 + o];
        h1[o] = fmaxf(acc, 0.f);
    }
    float h2[C2];
#pragma unroll
    for (int o = 0; o < C2; ++o) {
        float acc = b1[o];
#pragma unroll
        for (int k = 0; k < C1; ++k) acc += h1[k] * w1[k * C2 + o];
        h2[o] = fmaxf(acc, 0.f);
    }
    float hl[CL];
    if constexpr (C3 > 0) {
#pragma unroll
        for (int o = 0; o < C3; ++o) {
            float acc = b2[o];
#pragma unroll
            for (int k = 0; k < C2; ++k) acc += h2[k] * w2[k * C3 + o];
            hl[o] = fmaxf(acc, 0.f);
        }
    } else {
#pragma unroll
        for (int o = 0; o < CL; ++o) hl[o] = h2[o];
    }
    __shared__ float hs[64][CL + 1];
#pragma unroll
    for (int c = 0; c < CL; ++c) hs[tid][c] = hl[c];
    __syncthreads();
    for (int cc = 0; cc < CPB; ++cc) {
        for (int c = tid; c < CL; c += 64) {
            float mx = hs[cc * NS][c];
            for (int s2 = 1; s2 < NS; ++s2) mx = fmaxf(mx, hs[cc * NS + s2][c]);
            outf[(size_t)(blockIdx.x * CPB + cc) * CL + c] = mx;
        }
    }
}

// ---------------- build grouped input rows: [(p-c)/r | feats[n]] ----------------

__global__ void build_g(const float* __restrict__ xyz, const float* __restrict__ feats,
                        const float* __restrict__ centers, const int* __restrict__ idx,
                        float* __restrict__ g, int N, int M, int NS, int CF, float r) {
    const int row = blockIdx.x * 4 + (threadIdx.x >> 6);
    const int l   = threadIdx.x & 63;
    const int gc  = row / NS;
    const int b   = gc / M;
    const int n   = idx[row];
    const float* cp = centers + (size_t)gc * 3;
    const float* pp = xyz + ((size_t)b * N + n) * 3;
    float* go = g + (size_t)row * (3 + CF);
    if (l < 3) go[l] = (pp[l] - cp[l]) / r;
    for (int c = l; c < CF; c += 64) go[3 + c] = feats[((size_t)b * N + n) * CF + c];
}

// ---------------- dense layer + relu ----------------

__global__ void dense_relu(const float* __restrict__ X, const float* __restrict__ Wm,
                           const float* __restrict__ bias, float* __restrict__ Y,
                           int M, int CI, int CO) {
    const int co = blockIdx.x * 64 + threadIdx.x;
    const int m  = blockIdx.y * 4 + threadIdx.y;
    const float* x = X + (size_t)m * CI;
    float acc = bias[co];
#pragma unroll 4
    for (int k = 0; k < CI; ++k) acc += x[k] * Wm[(size_t)k * CO + co];
    Y[(size_t)m * CO + co] = fmaxf(acc, 0.f);
}

// ---------------- max over samples ----------------

__global__ void max_ns(const float* __restrict__ H, float* __restrict__ F,
                       int BM, int NS, int C) {
    const int tid = blockIdx.x * 256 + threadIdx.x;
    if (tid >= BM * C) return;
    const int bm = tid / C, c = tid % C;
    const float* h = H + ((size_t)bm * NS) * C + c;
    float mx = h[0];
    for (int s = 1; s < NS; ++s) mx = fmaxf(mx, h[(size_t)s * C]);
    F[tid] = mx;
}

// ---------------- FP: 3-NN + inverse-distance weights ----------------

__global__ void fp_nn(const float* __restrict__ unk, const float* __restrict__ kn,
                      int* __restrict__ nni, float* __restrict__ nnw, int NU, int NK) {
    const int t = blockIdx.x * blockDim.x + threadIdx.x;
    const int b = t / NU;
    const float* u = unk + (size_t)t * 3;
    const float ax = u[0], ay = u[1], az = u[2];
    const float sa_ = sum3sq(ax, ay, az);
    const float* K = kn + (size_t)b * NK * 3;
    float v0 = 1e30f, v1 = 1e30f, v2 = 1e30f;
    int   j0 = 0, j1 = 0, j2 = 0;
    for (int k = 0; k < NK; ++k) {
        const float d2 = sqd_dot(ax, ay, az, sa_, K[k * 3], K[k * 3 + 1], K[k * 3 + 2]);
        if (d2 < v0)      { v2 = v1; j2 = j1; v1 = v0; j1 = j0; v0 = d2; j0 = k; }
        else if (d2 < v1) { v2 = v1; j2 = j1; v1 = d2; j1 = k; }
        else if (d2 < v2) { v2 = d2; j2 = k; }
    }
    const float d0 = fmaxf(v0, 0.f), d1 = fmaxf(v1, 0.f), dd2 = fmaxf(v2, 0.f);
    float w0 = 1.f / (d0 + 1e-8f), w1 = 1.f / (d1 + 1e-8f), w2 = 1.f / (dd2 + 1e-8f);
    const float s = (w0 + w1) + w2;
    nnw[t * 3] = w0 / s; nnw[t * 3 + 1] = w1 / s; nnw[t * 3 + 2] = w2 / s;
    nni[t * 3] = j0; nni[t * 3 + 1] = j1; nni[t * 3 + 2] = j2;
}

// ---------------- FP: concat [feats1 | interp(feats2)] ----------------

__global__ void interp_concat(const float* __restrict__ f1, const float* __restrict__ f2,
                              const int* __restrict__ nni, const float* __restrict__ nnw,
                              float* __restrict__ X, int NU, int NK, int C1c, int C2c) {
    const int row = blockIdx.x * 4 + (threadIdx.x >> 6);
    const int l   = threadIdx.x & 63;
    const int b   = row / NU;
    const int i0 = nni[row * 3], i1 = nni[row * 3 + 1], i2 = nni[row * 3 + 2];
    const float w0 = nnw[row * 3], w1 = nnw[row * 3 + 1], w2 = nnw[row * 3 + 2];
    float* xo = X + (size_t)row * (C1c + C2c);
    for (int c = l; c < C1c; c += 64) xo[c] = f1[(size_t)row * C1c + c];
    const float* a  = f2 + ((size_t)b * NK + i0) * C2c;
    const float* bb = f2 + ((size_t)b * NK + i1) * C2c;
    const float* cc = f2 + ((size_t)b * NK + i2) * C2c;
    for (int c = l; c < C2c; c += 64) xo[C1c + c] = (w0 * a[c] + w1 * bb[c]) + w2 * cc[c];
}

__global__ void copyf(const float* __restrict__ src, float* __restrict__ dst, int n) {
    const int i = blockIdx.x * 256 + threadIdx.x;
    if (i < n) dst[i] = src[i];
}

// ---------------- host launcher ----------------

extern "C" void kernel_launch(void* const* d_in, const int* in_sizes, int n_in,
                              void* d_out, int out_size, void* d_ws, size_t ws_size,
                              hipStream_t stream) {
    const float* xyz  = (const float*)d_in[0];
    const float* s1w0 = (const float*)d_in[1],  *s1b0 = (const float*)d_in[2];
    const float* s1w1 = (const float*)d_in[3],  *s1b1 = (const float*)d_in[4];
    const float* s1w2 = (const float*)d_in[5],  *s1b2 = (const float*)d_in[6];
    const float* s2w0 = (const float*)d_in[7],  *s2b0 = (const float*)d_in[8];
    const float* s2w1 = (const float*)d_in[9],  *s2b1 = (const float*)d_in[10];
    const float* s3w0 = (const float*)d_in[11], *s3b0 = (const float*)d_in[12];
    const float* s3w1 = (const float*)d_in[13], *s3b1 = (const float*)d_in[14];
    const float* s4w0 = (const float*)d_in[15], *s4b0 = (const float*)d_in[16];
    const float* s4w1 = (const float*)d_in[17], *s4b1 = (const float*)d_in[18];
    const float* p1w0 = (const float*)d_in[19], *p1b0 = (const float*)d_in[20];
    const float* p1w1 = (const float*)d_in[21], *p1b1 = (const float*)d_in[22];
    const float* p2w0 = (const float*)d_in[23], *p2b0 = (const float*)d_in[24];
    const float* p2w1 = (const float*)d_in[25], *p2b1 = (const float*)d_in[26];
    float* out = (float*)d_out;
    float* W = (float*)d_ws;

    size_t off = 0;
    auto A_ = [&](size_t n) { size_t o = off; off += (n + 63) & ~(size_t)63; return o; };
    const size_t o_inds1 = A_(4 * 512);
    const size_t o_xyz1  = A_(4 * 512 * 3);
    const size_t o_idx1  = A_(4 * 512 * 64);
    const size_t o_f1    = A_(4 * 512 * 64);
    const size_t o_inds2 = A_(4 * 256);
    const size_t o_xyz2  = A_(4 * 256 * 3);
    const size_t o_idx2  = A_(4 * 256 * 32);
    const size_t o_f2    = A_(4 * 256 * 128);
    const size_t o_inds3 = A_(4 * 64);
    const size_t o_xyz3  = A_(4 * 64 * 3);
    const size_t o_idx3  = A_(4 * 64 * 16);
    const size_t o_f3    = A_(4 * 64 * 256);
    const size_t o_inds4 = A_(4 * 16);
    const size_t o_xyz4  = A_(4 * 16 * 3);
    const size_t o_idx4  = A_(4 * 16 * 16);
    const size_t o_f4    = A_(4 * 16 * 256);
    const size_t o_f5    = A_(4 * 64 * 128);
    const size_t o_nni1  = A_(4 * 64 * 3);
    const size_t o_nnw1  = A_(4 * 64 * 3);
    const size_t o_nni2  = A_(4 * 256 * 3);
    const size_t o_nnw2  = A_(4 * 256 * 3);
    const size_t o_sort  = A_((size_t)4 * 32768 * 4);  // float4 sorted points
    const size_t o_bufA  = A_((size_t)32768 * 128);    // 16 MiB arena
    const size_t o_bufB  = A_((size_t)32768 * 64);     //  8 MiB arena
    if (off * sizeof(float) > ws_size) return;  // fail loudly (validation will catch)

    int*   inds1 = (int*)(W + o_inds1); float* xyz1 = W + o_xyz1;
    int*   idx1  = (int*)(W + o_idx1);  float* f1   = W + o_f1;
    int*   inds2 = (int*)(W + o_inds2); float* xyz2 = W + o_xyz2;
    int*   idx2  = (int*)(W + o_idx2);  float* f2   = W + o_f2;
    int*   inds3 = (int*)(W + o_inds3); float* xyz3 = W + o_xyz3;
    int*   idx3  = (int*)(W + o_idx3);  float* f3   = W + o_f3;
    int*   inds4 = (int*)(W + o_inds4); float* xyz4 = W + o_xyz4;
    int*   idx4  = (int*)(W + o_idx4);  float* f4   = W + o_f4;
    float* f5    = W + o_f5;
    int*   nni1  = (int*)(W + o_nni1);  float* nnw1 = W + o_nnw1;
    int*   nni2  = (int*)(W + o_nni2);  float* nnw2 = W + o_nnw2;
    float4* sortP = (float4*)(W + o_sort);
    float* bufA  = W + o_bufA;
    float* bufB  = W + o_bufB;

    // -------- sa1: npoint=512, r=0.1, ns=64, MLP 3->32->32->64 --------
    fps_queue<<<4, 512, 0, stream>>>(xyz, inds1, sortP);
    gather3<<<8, 256, 0, stream>>>(xyz, inds1, xyz1, 32768, 512, 2048);
    ball_query_k<64><<<512, 256, 0, stream>>>(xyz, xyz1, idx1, 32768, 512, (float)(0.1 * 0.1));
    sa_fused<64, 0, 32, 32, 64><<<2048, 64, 0, stream>>>(
        xyz, nullptr, xyz1, idx1, s1w0, s1b0, s1w1, s1b1, s1w2, s1b2, f1, 32768, 512, 0.1f);

    // -------- sa2: npoint=256, r=0.2, ns=32, MLP 67->64->128 --------
    fps_small<512, 256><<<4, 64, 0, stream>>>(xyz1, inds2);
    gather3<<<4, 256, 0, stream>>>(xyz1, inds2, xyz2, 512, 256, 1024);
    ball_query_k<32><<<256, 256, 0, stream>>>(xyz1, xyz2, idx2, 512, 256, (float)(0.2 * 0.2));
    build_g<<<32768 / 4, 256, 0, stream>>>(xyz1, f1, xyz2, idx2, bufA, 512, 256, 32, 64, 0.2f);
    dense_relu<<<dim3(1, 32768 / 4), dim3(64, 4), 0, stream>>>(bufA, s2w0, s2b0, bufB, 32768, 67, 64);
    dense_relu<<<dim3(2, 32768 / 4), dim3(64, 4), 0, stream>>>(bufB, s2w1, s2b1, bufA, 32768, 64, 128);
    max_ns<<<(1024 * 128 + 255) / 256, 256, 0, stream>>>(bufA, f2, 1024, 32, 128);

    // -------- sa3: npoint=64, r=0.4, ns=16, MLP 131->128->256 --------
    fps_small<256, 64><<<4, 64, 0, stream>>>(xyz2, inds3);
    gather3<<<1, 256, 0, stream>>>(xyz2, inds3, xyz3, 256, 64, 256);
    ball_query_k<16><<<64, 256, 0, stream>>>(xyz2, xyz3, idx3, 256, 64, (float)(0.4 * 0.4));
    build_g<<<4096 / 4, 256, 0, stream>>>(xyz2, f2, xyz3, idx3, bufA, 256, 64, 16, 128, 0.4f);
    dense_relu<<<dim3(2, 4096 / 4), dim3(64, 4), 0, stream>>>(bufA, s3w0, s3b0, bufB, 4096, 131, 128);
    dense_relu<<<dim3(4, 4096 / 4), dim3(64, 4), 0, stream>>>(bufB, s3w1, s3b1, bufA, 4096, 128, 256);
    max_ns<<<(256 * 256 + 255) / 256, 256, 0, stream>>>(bufA, f3, 256, 16, 256);

    // -------- sa4: npoint=16, r=0.8, ns=16, MLP 259->256->256 --------
    fps_small<64, 16><<<4, 64, 0, stream>>>(xyz3, inds4);
    gather3<<<1, 256, 0, stream>>>(xyz3, inds4, xyz4, 64, 16, 64);
    ball_query_k<16><<<16, 256, 0, stream>>>(xyz3, xyz4, idx4, 64, 16, (float)(0.8 * 0.8));
    build_g<<<1024 / 4, 256, 0, stream>>>(xyz3, f3, xyz4, idx4, bufA, 64, 16, 16, 256, 0.8f);
    dense_relu<<<dim3(4, 1024 / 4), dim3(64, 4), 0, stream>>>(bufA, s4w0, s4b0, bufB, 1024, 259, 256);
    dense_relu<<<dim3(4, 1024 / 4), dim3(64, 4), 0, stream>>>(bufB, s4w1, s4b1, bufA, 1024, 256, 256);
    max_ns<<<(64 * 256 + 255) / 256, 256, 0, stream>>>(bufA, f4, 64, 16, 256);

    // -------- fp1: xyz3 <- xyz4, [f3 | interp(f4)] 512->256->128 --------
    fp_nn<<<1, 256, 0, stream>>>(xyz3, xyz4, nni1, nnw1, 64, 16);
    interp_concat<<<256 / 4, 256, 0, stream>>>(f3, f4, nni1, nnw1, bufA, 64, 16, 256, 256);
    dense_relu<<<dim3(4, 256 / 4), dim3(64, 4), 0, stream>>>(bufA, p1w0, p1b0, bufB, 256, 512, 256);
    dense_relu<<<dim3(2, 256 / 4), dim3(64, 4), 0, stream>>>(bufB, p1w1, p1b1, f5, 256, 256, 128);

    // -------- fp2: xyz2 <- xyz3, [f2 | interp(f5)] 256->128->64 --------
    fp_nn<<<4, 256, 0, stream>>>(xyz2, xyz3, nni2, nnw2, 256, 64);
    interp_concat<<<1024 / 4, 256, 0, stream>>>(f2, f5, nni2, nnw2, bufA, 256, 64, 128, 128);
    dense_relu<<<dim3(2, 1024 / 4), dim3(64, 4), 0, stream>>>(bufA, p2w0, p2b0, bufB, 1024, 256, 128);
    dense_relu<<<dim3(1, 1024 / 4), dim3(64, 4), 0, stream>>>(bufB, p2w1, p2b1, out, 1024, 128, 64);

    // -------- outputs: [f (4x256x64) | xyz2 (4x256x3)] --------
    copyf<<<12, 256, 0, stream>>>(xyz2, out + 65536, 3072);
}

// Round 6
// 2218.159 us; speedup vs baseline: 3.7038x; 1.5154x over previous
//
#include <hip/hip_runtime.h>
#include <cstddef>

// ---------------- numerics helpers (mirror reference FP32 op order) ----------------

__device__ __forceinline__ float sqd(float x, float y, float z, float qx, float qy, float qz) {
#pragma clang fp contract(off)
    float dx = x - qx, dy = y - qy, dz = z - qz;
    return (dx * dx + dy * dy) + dz * dz;
}

__device__ __forceinline__ float sum3sq(float x, float y, float z) {
#pragma clang fp contract(off)
    return (x * x + y * y) + z * z;
}

// reference _sqdist: sum(a^2) + sum(b^2) - 2*dot(a,b)
__device__ __forceinline__ float sqd_dot(float ax, float ay, float az, float sa_,
                                         float bx, float by, float bz) {
#pragma clang fp contract(off)
    float sb = (bx * bx + by * by) + bz * bz;
    float dt = (ax * bx + ay * by) + az * bz;
    return (sa_ + sb) - 2.0f * dt;
}

// packed argmax key: (float bits of val << 32) | ~orig. mind >= 0 so float bits are
// monotonic; max key == (val desc, orig asc) == reference first-occurrence argmax.
__device__ __forceinline__ unsigned long long packkey(float v, int orig) {
    return ((unsigned long long)__float_as_uint(v) << 32) | (unsigned)(~orig);
}

// ---------------- FPS large (N=32768, npoint=512): bucket pruning, 16-lane subgroups ----
// One 512-thread block per batch. Points bucket-sorted (8x8x8 over per-batch bbox) into SP
// as float4{x,y,z,bitcast(origidx)}; mind[] in LDS, sorted order. Per iteration:
//  (1) thread t tests bucket t (skip iff d2min(q,box) >= cached bmax: provable fminf
//      no-op, conservative margin); wave-aggregated push of active ids into LDS queue.
//  (2) 32 16-lane subgroups pull queue entries: coalesced SP + mind scan, packed-key
//      4-step reduce, lane0-of-group refreshes bucket cache (bkeyS + coords).
//  (3) block argmax over 512 cached packed keys (wave reduce + 8-entry scan); winner
//      coords from LDS. Exact reference semantics via packed keys everywhere.

__global__ __launch_bounds__(512) void fps_sub(const float* __restrict__ xyz,
                                               int* __restrict__ inds,
                                               float4* __restrict__ SPall) {
    const int b = blockIdx.x, t = threadIdx.x, w = t >> 6, l = t & 63;
    const float* __restrict__ P = xyz + (size_t)b * 32768 * 3;
    float4* __restrict__ SP = SPall + (size_t)b * 32768;

    __shared__ float mind[32768];
    __shared__ int   cntS[512], offS[512], curS[512];   // curS reused as work queue
    __shared__ unsigned long long bkeyS[512];
    __shared__ float bxS[512], byS[512], bzS[512];
    __shared__ unsigned long long candK[8];
    __shared__ int   candB[8];
    __shared__ float bbS[6];
    __shared__ float scr[48];
    __shared__ int   qcntS;

    // ---- pass 1: per-batch bbox ----
    float mnx = 1e30f, mny = 1e30f, mnz = 1e30f;
    float mxx = -1e30f, mxy = -1e30f, mxz = -1e30f;
    for (int p = t; p < 32768; p += 512) {
        const float x = P[3 * p], y = P[3 * p + 1], z = P[3 * p + 2];
        mnx = fminf(mnx, x); mxx = fmaxf(mxx, x);
        mny = fminf(mny, y); mxy = fmaxf(mxy, y);
        mnz = fminf(mnz, z); mxz = fmaxf(mxz, z);
    }
#pragma unroll
    for (int o = 1; o < 64; o <<= 1) {
        mnx = fminf(mnx, __shfl_xor(mnx, o)); mxx = fmaxf(mxx, __shfl_xor(mxx, o));
        mny = fminf(mny, __shfl_xor(mny, o)); mxy = fmaxf(mxy, __shfl_xor(mxy, o));
        mnz = fminf(mnz, __shfl_xor(mnz, o)); mxz = fmaxf(mxz, __shfl_xor(mxz, o));
    }
    if (l == 0) {
        scr[w] = mnx; scr[8 + w] = mny; scr[16 + w] = mnz;
        scr[24 + w] = mxx; scr[32 + w] = mxy; scr[40 + w] = mxz;
    }
    __syncthreads();
    if (t == 0) {
        float a0 = 1e30f, a1 = 1e30f, a2 = 1e30f, a3 = -1e30f, a4 = -1e30f, a5 = -1e30f;
        for (int i = 0; i < 8; ++i) {
            a0 = fminf(a0, scr[i]);      a1 = fminf(a1, scr[8 + i]);
            a2 = fminf(a2, scr[16 + i]); a3 = fmaxf(a3, scr[24 + i]);
            a4 = fmaxf(a4, scr[32 + i]); a5 = fmaxf(a5, scr[40 + i]);
        }
        bbS[0] = a0; bbS[1] = a1; bbS[2] = a2; bbS[3] = a3; bbS[4] = a4; bbS[5] = a5;
        qcntS = 0;
    }
    __syncthreads();
    const float bx0 = bbS[0], by0 = bbS[1], bz0 = bbS[2];
    const float ex = bbS[3] - bx0, ey = bbS[4] - by0, ez = bbS[5] - bz0;
    const float ivx = ex > 1e-20f ? 8.0f / ex : 0.0f;
    const float ivy = ey > 1e-20f ? 8.0f / ey : 0.0f;
    const float ivz = ez > 1e-20f ? 8.0f / ez : 0.0f;

    // ---- pass 2: histogram ----
    cntS[t] = 0;
    __syncthreads();
    for (int p = t; p < 32768; p += 512) {
        const float x = P[3 * p], y = P[3 * p + 1], z = P[3 * p + 2];
        const int ix = min(7, (int)((x - bx0) * ivx));
        const int iy = min(7, (int)((y - by0) * ivy));
        const int iz = min(7, (int)((z - bz0) * ivz));
        atomicAdd(&cntS[(iz * 8 + iy) * 8 + ix], 1);
    }
    __syncthreads();

    // ---- exclusive scan (Hillis-Steele over 512) ----
    offS[t] = cntS[t];
    __syncthreads();
    for (int d = 1; d < 512; d <<= 1) {
        const int v = (t >= d) ? offS[t - d] : 0;
        __syncthreads();
        offS[t] += v;
        __syncthreads();
    }
    const int myexc = offS[t] - cntS[t];
    offS[t] = myexc;
    curS[t] = myexc;
    __syncthreads();

    // ---- pass 3: scatter ----
    for (int p = t; p < 32768; p += 512) {
        const float x = P[3 * p], y = P[3 * p + 1], z = P[3 * p + 2];
        const int ix = min(7, (int)((x - bx0) * ivx));
        const int iy = min(7, (int)((y - by0) * ivy));
        const int iz = min(7, (int)((z - bz0) * ivz));
        const int pos = atomicAdd(&curS[(iz * 8 + iy) * 8 + ix], 1);
        SP[pos] = make_float4(x, y, z, __int_as_float(p));
    }
    // ---- init mind + per-bucket caches ----
    for (int s = t; s < 32768; s += 512) mind[s] = 1e30f;
    const int myCnt = cntS[t];
    bkeyS[t] = (myCnt > 0) ? packkey(1e30f, 0x7fffffff) : 0ull;
    bxS[t] = 0.f; byS[t] = 0.f; bzS[t] = 0.f;
    if (t == 0) inds[b * 512] = 0;

    // per-thread cell box (registers only)
    const int oix = t & 7, oiy = (t >> 3) & 7, oiz = t >> 6;
    const float gwx = ex * 0.125f, gwy = ey * 0.125f, gwz = ez * 0.125f;
    const float x0o = bx0 + oix * gwx, x1o = x0o + gwx;
    const float y0o = by0 + oiy * gwy, y1o = y0o + gwy;
    const float z0o = bz0 + oiz * gwz, z1o = z0o + gwz;

    const int g  = l >> 4;        // subgroup within wave (0..3)
    const int lg = l & 15;        // lane within subgroup
    const int sg = w * 4 + g;     // global subgroup id (0..31)

    float qx = P[0], qy = P[1], qz = P[2];
    __syncthreads();   // SP + mind + caches ready

    for (int k = 1; k < 512; ++k) {
        // ---- (1) test own bucket; wave-aggregated push ----
        const float ddx = fmaxf(fmaxf(x0o - qx, qx - x1o), 0.0f);
        const float ddy = fmaxf(fmaxf(y0o - qy, qy - y1o), 0.0f);
        const float ddz = fmaxf(fmaxf(z0o - qz, qz - z1o), 0.0f);
        const float d2m = (ddx * ddx + ddy * ddy) + ddz * ddz;
        const float bm = __uint_as_float((unsigned)(bkeyS[t] >> 32));
        const bool act = (myCnt > 0) && (d2m <= bm * 1.0001f + 1e-9f);
        const unsigned long long pmask = __ballot(act);
        const int wcnt = __popcll(pmask);
        int wbase = 0;
        if (l == 0 && wcnt) wbase = atomicAdd(&qcntS, wcnt);
        wbase = __shfl(wbase, 0);
        if (act) curS[wbase + __popcll(pmask & ((1ull << l) - 1ull))] = t;
        __syncthreads();   // B1: queue complete
        const int A = qcntS;

        // ---- (2) process queue entries, 16-lane subgroups ----
        for (int e = sg; e < A; e += 32) {
            const int bu = curS[e];
            const int base = offS[bu], cnt = cntS[bu];
            unsigned long long key = 0ull;
            int klane = l;
            float cx = 0.f, cy = 0.f, cz = 0.f;
            for (int c = lg; c < cnt; c += 16) {
                const float4 pt = SP[base + c];
                const float m = mind[base + c];
                const float d2 = sqd(pt.x, pt.y, pt.z, qx, qy, qz);
                const float nm = fminf(m, d2);
                mind[base + c] = nm;
                const unsigned long long kk = packkey(nm, __float_as_int(pt.w));
                if (kk > key) { key = kk; cx = pt.x; cy = pt.y; cz = pt.z; }
            }
#pragma unroll
            for (int s = 1; s < 16; s <<= 1) {
                const unsigned long long ok = __shfl_xor(key, s);
                const int ol2 = __shfl_xor(klane, s);
                if (ok > key) { key = ok; klane = ol2; }
            }
            const float wx = __shfl(cx, klane), wy = __shfl(cy, klane), wz = __shfl(cz, klane);
            if (lg == 0) {
                bkeyS[bu] = key;
                bxS[bu] = wx; byS[bu] = wy; bzS[bu] = wz;
            }
        }
        __syncthreads();   // B2: caches refreshed

        // ---- (3) block argmax over 512 cached buckets ----
        unsigned long long key = bkeyS[t];
        int bu2 = t;
#pragma unroll
        for (int s = 1; s < 64; s <<= 1) {
            const unsigned long long ok = __shfl_xor(key, s);
            const int ob = __shfl_xor(bu2, s);
            if (ok > key) { key = ok; bu2 = ob; }
        }
        if (l == 0) { candK[w] = key; candB[w] = bu2; }
        if (t == 0) qcntS = 0;
        __syncthreads();   // B3: candidates visible, queue reset
        unsigned long long wk = candK[0]; int wb = candB[0];
#pragma unroll
        for (int j = 1; j < 8; ++j) {
            const unsigned long long k2 = candK[j];
            if (k2 > wk) { wk = k2; wb = candB[j]; }
        }
        if (t == 0) inds[b * 512 + k] = ~(unsigned)wk;   // fire-and-forget
        qx = bxS[wb]; qy = byS[wb]; qz = bzS[wb];
        // bxS/cand reads complete before any thread passes next B1 -> safe
    }
}

// ---------------- FPS, small (N<=512), one wave per batch, all in registers ----------------

template <int N, int NPOINT>
__global__ __launch_bounds__(64) void fps_small(const float* __restrict__ pts,
                                                int* __restrict__ inds) {
    constexpr int PPT = N / 64;
    const int b = blockIdx.x, l = threadIdx.x;
    const float* __restrict__ P = pts + (size_t)b * N * 3;
    float px[PPT], py[PPT], pz[PPT], md[PPT];
#pragma unroll
    for (int j = 0; j < PPT; ++j) {
        const int p = l + 64 * j;
        px[j] = P[p * 3]; py[j] = P[p * 3 + 1]; pz[j] = P[p * 3 + 2];
        md[j] = 1e30f;
    }
    float qx = P[0], qy = P[1], qz = P[2];
    if (l == 0) inds[b * NPOINT] = 0;
    for (int k = 1; k < NPOINT; ++k) {
        float bv = -1.0f;
        int   bi = 0;
#pragma unroll
        for (int j = 0; j < PPT; ++j) {
            md[j] = fminf(md[j], sqd(px[j], py[j], pz[j], qx, qy, qz));
            if (md[j] > bv) { bv = md[j]; bi = l + 64 * j; }
        }
#pragma unroll
        for (int off = 1; off < 64; off <<= 1) {
            float ov = __shfl_xor(bv, off);
            int   oi = __shfl_xor(bi, off);
            if (ov > bv || (ov == bv && oi < bi)) { bv = ov; bi = oi; }
        }
        if (l == 0) inds[b * NPOINT + k] = bi;
        const int ol = bi & 63, js = bi >> 6;
        float sx = px[0], sy = py[0], sz = pz[0];
#pragma unroll
        for (int j = 1; j < PPT; ++j) {
            if (j == js) { sx = px[j]; sy = py[j]; sz = pz[j]; }
        }
        qx = __shfl(sx, ol); qy = __shfl(sy, ol); qz = __shfl(sz, ol);
    }
}

// ---------------- gather 3-float points by index ----------------

__global__ void gather3(const float* __restrict__ src, const int* __restrict__ inds,
                        float* __restrict__ dst, int Nsrc, int M, int total) {
    const int t = blockIdx.x * 256 + threadIdx.x;
    if (t >= total) return;
    const int b = t / M;
    const int n = inds[t];
    const float* s = src + ((size_t)b * Nsrc + n) * 3;
    float* d = dst + (size_t)t * 3;
    d[0] = s[0]; d[1] = s[1]; d[2] = s[2];
}

// ---------------- ball query: first NS points with d2 < r2, pad with first hit ----------------

template <int NS>
__global__ __launch_bounds__(256) void ball_query_k(const float* __restrict__ xyz,
                                                    const float* __restrict__ centers,
                                                    int* __restrict__ out,
                                                    int N, int M, float r2) {
    const int wv = blockIdx.x * 4 + (threadIdx.x >> 6);
    const int l  = threadIdx.x & 63;
    const int b  = wv / M;
    const float* cp = centers + (size_t)wv * 3;
    const float ax = cp[0], ay = cp[1], az = cp[2];
    const float sa_ = sum3sq(ax, ay, az);
    const float* __restrict__ P = xyz + (size_t)b * N * 3;
    int* o = out + (size_t)wv * NS;

    int cnt = 0, first = -1;
    float nx = P[l * 3], ny = P[l * 3 + 1], nz = P[l * 3 + 2];
    for (int i0 = 0; i0 < N; i0 += 64) {
        const float bx = nx, by = ny, bz = nz;
        if (i0 + 64 < N) {
            const int ip = (i0 + 64 + l) * 3;
            nx = P[ip]; ny = P[ip + 1]; nz = P[ip + 2];
        }
        const float d2 = sqd_dot(ax, ay, az, sa_, bx, by, bz);
        const bool in = d2 < r2;
        const unsigned long long mask = __ballot(in);
        if (first < 0 && mask != 0ull) first = i0 + __builtin_ctzll(mask);
        const int pos = cnt + __popcll(mask & ((1ull << l) - 1ull));
        if (in && pos < NS) o[pos] = i0 + l;
        cnt += __popcll(mask);
        if (cnt >= NS) break;
    }
    if (first < 0) first = 0;
    for (int p2 = cnt + l; p2 < NS; p2 += 64) o[p2] = first;
}

// ---------------- fused SA for sa1: gather + normalize + 3-layer MLP + max ----------------

template <int NS, int CF, int C1, int C2, int C3>
__global__ __launch_bounds__(64) void sa_fused(
    const float* __restrict__ xyz, const float* __restrict__ feats,
    const float* __restrict__ centers, const int* __restrict__ idx,
    const float* __restrict__ w0, const float* __restrict__ b0,
    const float* __restrict__ w1, const float* __restrict__ b1,
    const float* __restrict__ w2, const float* __restrict__ b2,
    float* __restrict__ outf, int N, int M, float r) {
    constexpr int CIN = 3 + CF;
    constexpr int CL  = (C3 > 0) ? C3 : C2;
    constexpr int CPB = 64 / NS;
    const int tid = threadIdx.x;
    const int ci = tid / NS, s = tid % NS;
    const int gc = blockIdx.x * CPB + ci;
    const int b  = gc / M;
    const float* cp = centers + (size_t)gc * 3;
    const float cx = cp[0], cy = cp[1], cz = cp[2];
    const int n = idx[(size_t)gc * NS + s];
    const float* pp = xyz + ((size_t)b * N + n) * 3;
    float gi[CIN];
    gi[0] = (pp[0] - cx) / r; gi[1] = (pp[1] - cy) / r; gi[2] = (pp[2] - cz) / r;
    if constexpr (CF > 0) {
        const float* fr = feats + ((size_t)b * N + n) * CF;
#pragma unroll
        for (int c = 0; c < CF; ++c) gi[3 + c] = fr[c];
    }
    float h1[C1];
#pragma unroll
    for (int o = 0; o < C1; ++o) {
        float acc = b0[o];
#pragma unroll
        for (int k = 0; k < CIN; ++k) acc += gi[k] * w0[k * C1 + o];
        h1[o] = fmaxf(acc, 0.f);
    }
    float h2[C2];
#pragma unroll
    for (int o = 0; o < C2; ++o) {
        float acc = b1[o];
#pragma unroll
        for (int k = 0; k < C1; ++k) acc += h1[k] * w1[k * C2 + o];
        h2[o] = fmaxf(acc, 0.f);
    }
    float hl[CL];
    if constexpr (C3 > 0) {
#pragma unroll
        for (int o = 0; o < C3; ++o) {
            float acc = b2[o];
#pragma unroll
            for (int k = 0; k < C2; ++k) acc += h2[k] * w2[k * C3 + o];
            hl[o] = fmaxf(acc, 0.f);
        }
    } else {
#pragma unroll
        for (int o = 0; o < CL; ++o) hl[o] = h2[o];
    }
    __shared__ float hs[64][CL + 1];
#pragma unroll
    for (int c = 0; c < CL; ++c) hs[tid][c] = hl[c];
    __syncthreads();
    for (int cc = 0; cc < CPB; ++cc) {
        for (int c = tid; c < CL; c += 64) {
            float mx = hs[cc * NS][c];
            for (int s2 = 1; s2 < NS; ++s2) mx = fmaxf(mx, hs[cc * NS + s2][c]);
            outf[(size_t)(blockIdx.x * CPB + cc) * CL + c] = mx;
        }
    }
}

// ---------------- build grouped input rows: [(p-c)/r | feats[n]] ----------------

__global__ void build_g(const float* __restrict__ xyz, const float* __restrict__ feats,
                        const float* __restrict__ centers, const int* __restrict__ idx,
                        float* __restrict__ g, int N, int M, int NS, int CF, float r) {
    const int row = blockIdx.x * 4 + (threadIdx.x >> 6);
    const int l   = threadIdx.x & 63;
    const int gc  = row / NS;
    const int b   = gc / M;
    const int n   = idx[row];
    const float* cp = centers + (size_t)gc * 3;
    const float* pp = xyz + ((size_t)b * N + n) * 3;
    float* go = g + (size_t)row * (3 + CF);
    if (l < 3) go[l] = (pp[l] - cp[l]) / r;
    for (int c = l; c < CF; c += 64) go[3 + c] = feats[((size_t)b * N + n) * CF + c];
}

// ---------------- dense layer + relu ----------------

__global__ void dense_relu(const float* __restrict__ X, const float* __restrict__ Wm,
                           const float* __restrict__ bias, float* __restrict__ Y,
                           int M, int CI, int CO) {
    const int co = blockIdx.x * 64 + threadIdx.x;
    const int m  = blockIdx.y * 4 + threadIdx.y;
    const float* x = X + (size_t)m * CI;
    float acc = bias[co];
#pragma unroll 4
    for (int k = 0; k < CI; ++k) acc += x[k] * Wm[(size_t)k * CO + co];
    Y[(size_t)m * CO + co] = fmaxf(acc, 0.f);
}

// ---------------- max over samples ----------------

__global__ void max_ns(const float* __restrict__ H, float* __restrict__ F,
                       int BM, int NS, int C) {
    const int tid = blockIdx.x * 256 + threadIdx.x;
    if (tid >= BM * C) return;
    const int bm = tid / C, c = tid % C;
    const float* h = H + ((size_t)bm * NS) * C + c;
    float mx = h[0];
    for (int s = 1; s < NS; ++s) mx = fmaxf(mx, h[(size_t)s * C]);
    F[tid] = mx;
}

// ---------------- FP: 3-NN + inverse-distance weights ----------------

__global__ void fp_nn(const float* __restrict__ unk, const float* __restrict__ kn,
                      int* __restrict__ nni, float* __restrict__ nnw, int NU, int NK) {
    const int t = blockIdx.x * blockDim.x + threadIdx.x;
    const int b = t / NU;
    const float* u = unk + (size_t)t * 3;
    const float ax = u[0], ay = u[1], az = u[2];
    const float sa_ = sum3sq(ax, ay, az);
    const float* K = kn + (size_t)b * NK * 3;
    float v0 = 1e30f, v1 = 1e30f, v2 = 1e30f;
    int   j0 = 0, j1 = 0, j2 = 0;
    for (int k = 0; k < NK; ++k) {
        const float d2 = sqd_dot(ax, ay, az, sa_, K[k * 3], K[k * 3 + 1], K[k * 3 + 2]);
        if (d2 < v0)      { v2 = v1; j2 = j1; v1 = v0; j1 = j0; v0 = d2; j0 = k; }
        else if (d2 < v1) { v2 = v1; j2 = j1; v1 = d2; j1 = k; }
        else if (d2 < v2) { v2 = d2; j2 = k; }
    }
    const float d0 = fmaxf(v0, 0.f), d1 = fmaxf(v1, 0.f), dd2 = fmaxf(v2, 0.f);
    float w0 = 1.f / (d0 + 1e-8f), w1 = 1.f / (d1 + 1e-8f), w2 = 1.f / (dd2 + 1e-8f);
    const float s = (w0 + w1) + w2;
    nnw[t * 3] = w0 / s; nnw[t * 3 + 1] = w1 / s; nnw[t * 3 + 2] = w2 / s;
    nni[t * 3] = j0; nni[t * 3 + 1] = j1; nni[t * 3 + 2] = j2;
}

// ---------------- FP: concat [feats1 | interp(feats2)] ----------------

__global__ void interp_concat(const float* __restrict__ f1, const float* __restrict__ f2,
                              const int* __restrict__ nni, const float* __restrict__ nnw,
                              float* __restrict__ X, int NU, int NK, int C1c, int C2c) {
    const int row = blockIdx.x * 4 + (threadIdx.x >> 6);
    const int l   = threadIdx.x & 63;
    const int b   = row / NU;
    const int i0 = nni[row * 3], i1 = nni[row * 3 + 1], i2 = nni[row * 3 + 2];
    const float w0 = nnw[row * 3], w1 = nnw[row * 3 + 1], w2 = nnw[row * 3 + 2];
    float* xo = X + (size_t)row * (C1c + C2c);
    for (int c = l; c < C1c; c += 64) xo[c] = f1[(size_t)row * C1c + c];
    const float* a  = f2 + ((size_t)b * NK + i0) * C2c;
    const float* bb = f2 + ((size_t)b * NK + i1) * C2c;
    const float* cc = f2 + ((size_t)b * NK + i2) * C2c;
    for (int c = l; c < C2c; c += 64) xo[C1c + c] = (w0 * a[c] + w1 * bb[c]) + w2 * cc[c];
}

__global__ void copyf(const float* __restrict__ src, float* __restrict__ dst, int n) {
    const int i = blockIdx.x * 256 + threadIdx.x;
    if (i < n) dst[i] = src[i];
}

// ---------------- host launcher ----------------

extern "C" void kernel_launch(void* const* d_in, const int* in_sizes, int n_in,
                              void* d_out, int out_size, void* d_ws, size_t ws_size,
                              hipStream_t stream) {
    const float* xyz  = (const float*)d_in[0];
    const float* s1w0 = (const float*)d_in[1],  *s1b0 = (const float*)d_in[2];
    const float* s1w1 = (const float*)d_in[3],  *s1b1 = (const float*)d_in[4];
    const float* s1w2 = (const float*)d_in[5],  *s1b2 = (const float*)d_in[6];
    const float* s2w0 = (const float*)d_in[7],  *s2b0 = (const float*)d_in[8];
    const float* s2w1 = (const float*)d_in[9],  *s2b1 = (const float*)d_in[10];
    const float* s3w0 = (const float*)d_in[11], *s3b0 = (const float*)d_in[12];
    const float* s3w1 = (const float*)d_in[13], *s3b1 = (const float*)d_in[14];
    const float* s4w0 = (const float*)d_in[15], *s4b0 = (const float*)d_in[16];
    const float* s4w1 = (const float*)d_in[17], *s4b1 = (const float*)d_in[18];
    const float* p1w0 = (const float*)d_in[19], *p1b0 = (const float*)d_in[20];
    const float* p1w1 = (const float*)d_in[21], *p1b1 = (const float*)d_in[22];
    const float* p2w0 = (const float*)d_in[23], *p2b0 = (const float*)d_in[24];
    const float* p2w1 = (const float*)d_in[25], *p2b1 = (const float*)d_in[26];
    float* out = (float*)d_out;
    float* W = (float*)d_ws;

    size_t off = 0;
    auto A_ = [&](size_t n) { size_t o = off; off += (n + 63) & ~(size_t)63; return o; };
    const size_t o_inds1 = A_(4 * 512);
    const size_t o_xyz1  = A_(4 * 512 * 3);
    const size_t o_idx1  = A_(4 * 512 * 64);
    const size_t o_f1    = A_(4 * 512 * 64);
    const size_t o_inds2 = A_(4 * 256);
    const size_t o_xyz2  = A_(4 * 256 * 3);
    const size_t o_idx2  = A_(4 * 256 * 32);
    const size_t o_f2    = A_(4 * 256 * 128);
    const size_t o_inds3 = A_(4 * 64);
    const size_t o_xyz3  = A_(4 * 64 * 3);
    const size_t o_idx3  = A_(4 * 64 * 16);
    const size_t o_f3    = A_(4 * 64 * 256);
    const size_t o_inds4 = A_(4 * 16);
    const size_t o_xyz4  = A_(4 * 16 * 3);
    const size_t o_idx4  = A_(4 * 16 * 16);
    const size_t o_f4    = A_(4 * 16 * 256);
    const size_t o_f5    = A_(4 * 64 * 128);
    const size_t o_nni1  = A_(4 * 64 * 3);
    const size_t o_nnw1  = A_(4 * 64 * 3);
    const size_t o_nni2  = A_(4 * 256 * 3);
    const size_t o_nnw2  = A_(4 * 256 * 3);
    const size_t o_sort  = A_((size_t)4 * 32768 * 4);  // float4 sorted points
    const size_t o_bufA  = A_((size_t)32768 * 128);    // 16 MiB arena
    const size_t o_bufB  = A_((size_t)32768 * 64);     //  8 MiB arena
    if (off * sizeof(float) > ws_size) return;  // fail loudly (validation will catch)

    int*   inds1 = (int*)(W + o_inds1); float* xyz1 = W + o_xyz1;
    int*   idx1  = (int*)(W + o_idx1);  float* f1   = W + o_f1;
    int*   inds2 = (int*)(W + o_inds2); float* xyz2 = W + o_xyz2;
    int*   idx2  = (int*)(W + o_idx2);  float* f2   = W + o_f2;
    int*   inds3 = (int*)(W + o_inds3); float* xyz3 = W + o_xyz3;
    int*   idx3  = (int*)(W + o_idx3);  float* f3   = W + o_f3;
    int*   inds4 = (int*)(W + o_inds4); float* xyz4 = W + o_xyz4;
    int*   idx4  = (int*)(W + o_idx4);  float* f4   = W + o_f4;
    float* f5    = W + o_f5;
    int*   nni1  = (int*)(W + o_nni1);  float* nnw1 = W + o_nnw1;
    int*   nni2  = (int*)(W + o_nni2);  float* nnw2 = W + o_nnw2;
    float4* sortP = (float4*)(W + o_sort);
    float* bufA  = W + o_bufA;
    float* bufB  = W + o_bufB;

    // -------- sa1: npoint=512, r=0.1, ns=64, MLP 3->32->32->64 --------
    fps_sub<<<4, 512, 0, stream>>>(xyz, inds1, sortP);
    gather3<<<8, 256, 0, stream>>>(xyz, inds1, xyz1, 32768, 512, 2048);
    ball_query_k<64><<<512, 256, 0, stream>>>(xyz, xyz1, idx1, 32768, 512, (float)(0.1 * 0.1));
    sa_fused<64, 0, 32, 32, 64><<<2048, 64, 0, stream>>>(
        xyz, nullptr, xyz1, idx1, s1w0, s1b0, s1w1, s1b1, s1w2, s1b2, f1, 32768, 512, 0.1f);

    // -------- sa2: npoint=256, r=0.2, ns=32, MLP 67->64->128 --------
    fps_small<512, 256><<<4, 64, 0, stream>>>(xyz1, inds2);
    gather3<<<4, 256, 0, stream>>>(xyz1, inds2, xyz2, 512, 256, 1024);
    ball_query_k<32><<<256, 256, 0, stream>>>(xyz1, xyz2, idx2, 512, 256, (float)(0.2 * 0.2));
    build_g<<<32768 / 4, 256, 0, stream>>>(xyz1, f1, xyz2, idx2, bufA, 512, 256, 32, 64, 0.2f);
    dense_relu<<<dim3(1, 32768 / 4), dim3(64, 4), 0, stream>>>(bufA, s2w0, s2b0, bufB, 32768, 67, 64);
    dense_relu<<<dim3(2, 32768 / 4), dim3(64, 4), 0, stream>>>(bufB, s2w1, s2b1, bufA, 32768, 64, 128);
    max_ns<<<(1024 * 128 + 255) / 256, 256, 0, stream>>>(bufA, f2, 1024, 32, 128);

    // -------- sa3: npoint=64, r=0.4, ns=16, MLP 131->128->256 --------
    fps_small<256, 64><<<4, 64, 0, stream>>>(xyz2, inds3);
    gather3<<<1, 256, 0, stream>>>(xyz2, inds3, xyz3, 256, 64, 256);
    ball_query_k<16><<<64, 256, 0, stream>>>(xyz2, xyz3, idx3, 256, 64, (float)(0.4 * 0.4));
    build_g<<<4096 / 4, 256, 0, stream>>>(xyz2, f2, xyz3, idx3, bufA, 256, 64, 16, 128, 0.4f);
    dense_relu<<<dim3(2, 4096 / 4), dim3(64, 4), 0, stream>>>(bufA, s3w0, s3b0, bufB, 4096, 131, 128);
    dense_relu<<<dim3(4, 4096 / 4), dim3(64, 4), 0, stream>>>(bufB, s3w1, s3b1, bufA, 4096, 128, 256);
    max_ns<<<(256 * 256 + 255) / 256, 256, 0, stream>>>(bufA, f3, 256, 16, 256);

    // -------- sa4: npoint=16, r=0.8, ns=16, MLP 259->256->256 --------
    fps_small<64, 16><<<4, 64, 0, stream>>>(xyz3, inds4);
    gather3<<<1, 256, 0, stream>>>(xyz3, inds4, xyz4, 64, 16, 64);
    ball_query_k<16><<<16, 256, 0, stream>>>(xyz3, xyz4, idx4, 64, 16, (float)(0.8 * 0.8));
    build_g<<<1024 / 4, 256, 0, stream>>>(xyz3, f3, xyz4, idx4, bufA, 64, 16, 16, 256, 0.8f);
    dense_relu<<<dim3(4, 1024 / 4), dim3(64, 4), 0, stream>>>(bufA, s4w0, s4b0, bufB, 1024, 259, 256);
    dense_relu<<<dim3(4, 1024 / 4), dim3(64, 4), 0, stream>>>(bufB, s4w1, s4b1, bufA, 1024, 256, 256);
    max_ns<<<(64 * 256 + 255) / 256, 256, 0, stream>>>(bufA, f4, 64, 16, 256);

    // -------- fp1: xyz3 <- xyz4, [f3 | interp(f4)] 512->256->128 --------
    fp_nn<<<1, 256, 0, stream>>>(xyz3, xyz4, nni1, nnw1, 64, 16);
    interp_concat<<<256 / 4, 256, 0, stream>>>(f3, f4, nni1, nnw1, bufA, 64, 16, 256, 256);
    dense_relu<<<dim3(4, 256 / 4), dim3(64, 4), 0, stream>>>(bufA, p1w0, p1b0, bufB, 256, 512, 256);
    dense_relu<<<dim3(2, 256 / 4), dim3(64, 4), 0, stream>>>(bufB, p1w1, p1b1, f5, 256, 256, 128);

    // -------- fp2: xyz2 <- xyz3, [f2 | interp(f5)] 256->128->64 --------
    fp_nn<<<4, 256, 0, stream>>>(xyz2, xyz3, nni2, nnw2, 256, 64);
    interp_concat<<<1024 / 4, 256, 0, stream>>>(f2, f5, nni2, nnw2, bufA, 256, 64, 128, 128);
    dense_relu<<<dim3(2, 1024 / 4), dim3(64, 4), 0, stream>>>(bufA, p2w0, p2b0, bufB, 1024, 256, 128);
    dense_relu<<<dim3(1, 1024 / 4), dim3(64, 4), 0, stream>>>(bufB, p2w1, p2b1, out, 1024, 128, 64);

    // -------- outputs: [f (4x256x64) | xyz2 (4x256x3)] --------
    copyf<<<12, 256, 0, stream>>>(xyz2, out + 65536, 3072);
}